// Round 13
// baseline (781.189 us; speedup 1.0000x reference)
//
#include <hip/hip_runtime.h>
#include <hip/hip_bf16.h>
#include <math.h>

#define B_   32
#define L_   2048
#define D_   512
#define BLROWS (B_*L_)                 // 65536
#define NBIG ((size_t)BLROWS * D_)     // 33554432

typedef __hip_bfloat16 bf16;
using bf16x8 = __attribute__((ext_vector_type(8))) short;
using f32x4  = __attribute__((ext_vector_type(4))) float;

__device__ __forceinline__ unsigned short f2b(float f) {
  bf16 h = __float2bfloat16(f);
  return *reinterpret_cast<unsigned short*>(&h);
}
__device__ __forceinline__ float b2f(unsigned short u) {
  union { unsigned int i; float f; } c;
  c.i = ((unsigned int)u) << 16;
  return c.f;
}

__device__ __forceinline__ void gl_lds16(const void* g, void* l) {
  __builtin_amdgcn_global_load_lds(
      (const __attribute__((address_space(1))) void*)g,
      (__attribute__((address_space(3))) void*)l, 16, 0, 0);
}

// ---------------------------------------------------------------------------
// fp32 -> bf16 vectorized converter (weights only now)
// ---------------------------------------------------------------------------
__global__ __launch_bounds__(256) void f2bfK(const float4* __restrict__ src,
                                             ushort4* __restrict__ dst,
                                             size_t n4) {
  for (size_t i = (size_t)blockIdx.x * 256 + threadIdx.x; i < n4;
       i += (size_t)gridDim.x * 256) {
    float4 v = src[i];
    ushort4 o;
    o.x = f2b(v.x); o.y = f2b(v.y); o.z = f2b(v.z); o.w = f2b(v.w);
    dst[i] = o;
  }
}

// ---------------------------------------------------------------------------
// Twiddle tables.
// ---------------------------------------------------------------------------
__global__ __launch_bounds__(256) void genTwP(float* __restrict__ TwP) {
  int idx = blockIdx.x * 256 + threadIdx.x;   // l*64 + mg*16 + j ; 131072
  int l = idx >> 6, rem = idx & 63, mg = rem >> 4, j = rem & 15;
  int m = mg * 8 + (j & 7);
  int r = (m * l) & (L_ - 1);
  float ang = (float)r * (6.283185307179586f / (float)L_);
  TwP[idx] = (j < 8) ? cosf(ang) : -sinf(ang);
}

__global__ __launch_bounds__(256) void genTbF(float* __restrict__ Tb) {
  int idx = blockIdx.x * 256 + threadIdx.x;   // l*64 + j ; 131072
  int l = idx >> 6, j = idx & 63;
  int m = j >> 1;
  int r = (m * l) & (L_ - 1);
  float ang = (float)r * (6.283185307179586f / (float)L_);
  Tb[idx] = (j & 1) ? sinf(ang) : cosf(ang);
}

// TbD = Tb - movavg_l(Tb), emitted as bf16 (decomposed inverse basis)
__global__ __launch_bounds__(256) void genTbDbf(const float* __restrict__ Tb,
                                                bf16* __restrict__ TbD) {
  int idx = blockIdx.x * 256 + threadIdx.x;   // l*64 + j ; 131072
  int l = idx >> 6, j = idx & 63;
  float s = 0.f;
  for (int t = l - 64; t < l + 64; t++) {
    int cl = min(max(t, 0), L_ - 1);
    s += Tb[cl * 64 + j];
  }
  TbD[idx] = __float2bfloat16(Tb[idx] - s * (1.f / 128.f));
}

// ---------------------------------------------------------------------------
// Wf transpose: Wf_{r,i}[i][o][m] fp32 -> Wfm{R,I}[m][io] bf16  (io = i*512+o)
// ---------------------------------------------------------------------------
__global__ __launch_bounds__(256) void twWf(const float* __restrict__ Wfr,
                                            const float* __restrict__ Wfi,
                                            bf16* __restrict__ WfmR,
                                            bf16* __restrict__ WfmI) {
  __shared__ float tile[64][33];
  const size_t io0 = (size_t)blockIdx.x * 64;
#pragma unroll
  for (int arr = 0; arr < 2; arr++) {
    const float* src = arr ? Wfi : Wfr;
    bf16* dst = arr ? WfmI : WfmR;
#pragma unroll
    for (int s = 0; s < 8; s++) {
      int flat = s * 256 + threadIdx.x;
      int r = flat >> 5, m = flat & 31;
      tile[r][m] = src[(io0 + r) * 32 + m];
    }
    __syncthreads();
#pragma unroll
    for (int s = 0; s < 8; s++) {
      int flat = s * 256 + threadIdx.x;
      int m = flat >> 6, io = flat & 63;
      dst[(size_t)m * 262144 + io0 + io] = __float2bfloat16(tile[io][m]);
    }
    __syncthreads();
  }
}

// ---------------------------------------------------------------------------
// gemm_k64: 128x128 tile, BK=64, 256 thr (4 waves 2x2), 2-buf __syncthreads
// pipeline (replay-proven).  A: LDS, XOR-swizzled (R10/R11-verified
// conflict-free).  B: NOT staged — weights are 0.5 MB, L2-resident, shared
// by all blocks; fragments read directly from global (16 rows x 64 B
// contiguous per instruction).  bg loads issue BEFORE the A-prefetch
// gl_lds so their waitcnt is vmcnt(4), keeping the A stage in flight.
// LDS 32 KB/block -> 5 blocks/CU (was 2) for latency hiding.
// AFP32: A read fp32, reg-staged (cvt + ds_write_b128 to swizzled phys).
// Transposed MFMA (C^T = mfma(B,A)) -> d-major vectorized epilogue.
// Grid: 1-D 2048 blocks; XCD-pairing decode for A-panel L2 reuse.
// ---------------------------------------------------------------------------
template <bool GELU, bool RESID, bool BIAS, bool OUTBF, bool RESBF, bool AFP32>
__global__ __launch_bounds__(256) void gemm_k64(
    const void* __restrict__ Av, const bf16* __restrict__ Wt,
    const float* __restrict__ bias, const void* __restrict__ resid,
    void* __restrict__ Cout, int M, int N, int K) {
  __shared__ __align__(16) bf16 As[2][128 * 64];   // 16 KB each, 32 KB total
  const int t = threadIdx.x;
  const int lane = t & 63;
  const int w = t >> 6, wr = w >> 1, wc = w & 1;

  // XCD pairing: id = xcd + 8*(c + 4*rg); row-panel r = rg*8 + xcd.
  const int id = blockIdx.x;
  const int xcd = id & 7, rest = id >> 3;
  const int cb = rest & 3, rg = rest >> 2;
  const int row0 = (rg * 8 + xcd) * 128, col0 = cb * 128;

  const bf16* Ab = (const bf16*)Av;
  const float* Af = (const float*)Av;

  f32x4 acc[4][4];   // acc[n][m] = C^T fragment
#pragma unroll
  for (int i = 0; i < 4; i++)
#pragma unroll
    for (int j = 0; j < 4; j++) acc[i][j] = (f32x4){0.f, 0.f, 0.f, 0.f};

  // A staging: 1024 chunks (16B) per tile; thread t covers chunk
  // ci = s*256+t, row = ci>>3, global k-chunk c = ci&7, phys = c^(row&7).
  auto stage = [&](int buf, int k0) {
#pragma unroll
    for (int s = 0; s < 4; s++) {
      const int ci = s * 256 + t;
      const int row = ci >> 3;
      const int cg = ci & 7;
      if (AFP32) {
        const int pc = cg ^ (row & 7);
        const float* ax = Af + (size_t)(row0 + row) * K + k0 + cg * 8;
        float4 v0 = *(const float4*)(ax);
        float4 v1 = *(const float4*)(ax + 4);
        int4 wv;
        wv.x = (int)f2b(v0.x) | ((int)f2b(v0.y) << 16);
        wv.y = (int)f2b(v0.z) | ((int)f2b(v0.w) << 16);
        wv.z = (int)f2b(v1.x) | ((int)f2b(v1.y) << 16);
        wv.w = (int)f2b(v1.z) | ((int)f2b(v1.w) << 16);
        *(int4*)&As[buf][(size_t)(row * 8 + pc) * 8] = wv;
      } else {
        const int kqg = cg ^ (row & 7);
        bf16* dA = &As[buf][(size_t)(s * 256 + (t & ~63)) * 8];
        gl_lds16(Ab + (size_t)(row0 + row) * K + k0 + kqg * 8, dA);
      }
    }
  };

  stage(0, 0);
  int cur = 0;
  for (int k0 = 0; k0 < K; k0 += 64) {
    __syncthreads();                   // drains stage(cur); prev reads done
    // B fragments for this K-step straight from global (L2-resident),
    // issued FIRST so consuming them waits vmcnt(4), not the A prefetch.
    bf16x8 bg[2][4];
#pragma unroll
    for (int ks = 0; ks < 2; ks++)
#pragma unroll
      for (int n = 0; n < 4; n++) {
        const int rb = col0 + wc * 64 + n * 16 + (lane & 15);
        const int c = ks * 4 + (lane >> 4);
        bg[ks][n] = *reinterpret_cast<const bf16x8*>(
            Wt + (size_t)rb * K + k0 + c * 8);
      }
    if (k0 + 64 < K) stage(cur ^ 1, k0 + 64);
#pragma unroll
    for (int ks = 0; ks < 2; ks++) {
      const int c = ks * 4 + (lane >> 4);        // global k-chunk
      const int pc = c ^ (lane & 7);             // phys (swizzled) chunk
      bf16x8 af[4];
#pragma unroll
      for (int m = 0; m < 4; m++) {
        const int ra = wr * 64 + m * 16 + (lane & 15);
        af[m] = *reinterpret_cast<const bf16x8*>(&As[cur][(ra * 8 + pc) * 8]);
      }
#pragma unroll
      for (int n = 0; n < 4; n++)
#pragma unroll
        for (int m = 0; m < 4; m++)
          acc[n][m] = __builtin_amdgcn_mfma_f32_16x16x32_bf16(
              bg[ks][n], af[m], acc[n][m], 0, 0, 0);
    }
    cur ^= 1;
  }

  // transposed epilogue: d-major vector access
  float* Cf = (float*)Cout;
  ushort* Cb = (ushort*)Cout;
#pragma unroll
  for (int n = 0; n < 4; n++) {
    const int dbase = col0 + wc * 64 + n * 16 + ((lane >> 4) << 2);
    float4 bsv = {0.f, 0.f, 0.f, 0.f};
    if (BIAS) bsv = *(const float4*)(bias + dbase);
#pragma unroll
    for (int m = 0; m < 4; m++) {
      const size_t r = (size_t)row0 + wr * 64 + m * 16 + (lane & 15);
      float v[4];
#pragma unroll
      for (int j = 0; j < 4; j++) {
        float u = acc[n][m][j] + (BIAS ? (&bsv.x)[j] : 0.f);
        if (GELU) u = 0.5f * u * (1.0f + erff(u * 0.70710678118654752f));
        v[j] = u;
      }
      if (RESID) {
        if (RESBF) {
          ushort4 rv = *(const ushort4*)((const ushort*)resid + r * N + dbase);
          v[0] += b2f(rv.x); v[1] += b2f(rv.y);
          v[2] += b2f(rv.z); v[3] += b2f(rv.w);
        } else {
          float4 rv = *(const float4*)((const float*)resid + r * N + dbase);
          v[0] += rv.x; v[1] += rv.y; v[2] += rv.z; v[3] += rv.w;
        }
      }
      if (OUTBF) {
        ushort4 o = {f2b(v[0]), f2b(v[1]), f2b(v[2]), f2b(v[3])};
        *(ushort4*)(Cb + r * N + dbase) = o;
      } else {
        float4 o = {v[0], v[1], v[2], v[3]};
        *(float4*)(Cf + r * N + dbase) = o;
      }
    }
  }
}

// ---------------------------------------------------------------------------
// gemmD: xr[b][l][d] = u[b][l][d] + sum_j TbD[l][j] * CCT[b][d][j]
// ---------------------------------------------------------------------------
__global__ __launch_bounds__(256) void gemmD(
    const bf16* __restrict__ TbD, const bf16* __restrict__ CCT,
    const ushort* __restrict__ u, ushort* __restrict__ xr) {
  __shared__ __align__(16) bf16 As[128 * 64];
  __shared__ __align__(16) bf16 Bs[128 * 64];
  const int t = threadIdx.x;
  const int lane = t & 63;
  const int wid = t >> 6, wr = wid >> 1, wc = wid & 1;
  const int row0 = blockIdx.x * 128, col0 = blockIdx.y * 128;
  const int b = blockIdx.z;
  const bf16* Bsrc = CCT + (size_t)b * 512 * 64;

  const int srow = t >> 3, schk = t & 7;
  const int wb16 = (t & ~63) * 8;
#pragma unroll
  for (int p = 0; p < 4; p++) {
    gl_lds16(TbD + (size_t)(row0 + srow + 32 * p) * 64 + schk * 8,
             &As[p * 2048 + wb16]);
    gl_lds16(Bsrc + (size_t)(col0 + srow + 32 * p) * 64 + schk * 8,
             &Bs[p * 2048 + wb16]);
  }
  __syncthreads();

  f32x4 acc[4][4];
#pragma unroll
  for (int i = 0; i < 4; i++)
#pragma unroll
    for (int j = 0; j < 4; j++) acc[i][j] = (f32x4){0.f, 0.f, 0.f, 0.f};

#pragma unroll
  for (int ks = 0; ks < 2; ks++) {
    bf16x8 af[4], bg[4];
#pragma unroll
    for (int m = 0; m < 4; m++)
      af[m] = *reinterpret_cast<const bf16x8*>(
          &As[(wr * 64 + m * 16 + (lane & 15)) * 64 + ks * 32 +
              (lane >> 4) * 8]);
#pragma unroll
    for (int n = 0; n < 4; n++)
      bg[n] = *reinterpret_cast<const bf16x8*>(
          &Bs[(wc * 64 + n * 16 + (lane & 15)) * 64 + ks * 32 +
              (lane >> 4) * 8]);
#pragma unroll
    for (int n = 0; n < 4; n++)
#pragma unroll
      for (int m = 0; m < 4; m++)
        acc[n][m] = __builtin_amdgcn_mfma_f32_16x16x32_bf16(bg[n], af[m],
                                                            acc[n][m], 0, 0, 0);
  }

#pragma unroll
  for (int n = 0; n < 4; n++) {
    const int dbase = col0 + wc * 64 + n * 16 + ((lane >> 4) << 2);
#pragma unroll
    for (int m = 0; m < 4; m++) {
      const int l = row0 + wr * 64 + m * 16 + (lane & 15);
      const size_t rg = ((size_t)b * L_ + l) * D_ + dbase;
      ushort4 uv = *(const ushort4*)(u + rg);
      ushort4 o;
      o.x = f2b(acc[n][m][0] + b2f(uv.x));
      o.y = f2b(acc[n][m][1] + b2f(uv.y));
      o.z = f2b(acc[n][m][2] + b2f(uv.z));
      o.w = f2b(acc[n][m][3] + b2f(uv.w));
      *(ushort4*)(xr + rg) = o;
    }
  }
}

// ---------------------------------------------------------------------------
// gemm_bt (2-buf, for folds + CC GEMMs).  batchC offset in normal epilogue.
// EPI: 0 = normal, 1/2 = CCT real/imag write.
// ---------------------------------------------------------------------------
template <bool BIAS, bool OUTBF, bool MGUARD, int EPI>
__global__ __launch_bounds__(256) void gemm_bt(
    const bf16* __restrict__ A, const bf16* __restrict__ Wt,
    const float* __restrict__ bias, void* __restrict__ Cout,
    int M, int N, int K, long batchA, long batchB, long batchC,
    int ldc, int coff) {
  __shared__ __align__(16) bf16 As[2][128 * 32];
  __shared__ __align__(16) bf16 Bs[2][128 * 32];
  const int t = threadIdx.x;
  const int lane = t & 63;
  const int wid = t >> 6, wr = wid >> 1, wc = wid & 1;
  const int row0 = blockIdx.x * 128, col0 = blockIdx.y * 128;
  const int zb = blockIdx.z;
  A += (size_t)zb * (size_t)batchA;
  Wt += (size_t)zb * (size_t)batchB;

  f32x4 acc[4][4];
#pragma unroll
  for (int i = 0; i < 4; i++)
#pragma unroll
    for (int j = 0; j < 4; j++) acc[i][j] = (f32x4){0.f, 0.f, 0.f, 0.f};

  const int srow = t >> 2, scq = t & 3;
  const int sa0 = MGUARD ? (srow & 31) : srow;
  const int sa1 = MGUARD ? (srow & 31) : (64 + srow);
  const int wbase = (t & ~63) * 8;

  auto stage = [&](int buf, int k0) {
    gl_lds16(A + (size_t)(row0 + sa0) * K + k0 + scq * 8, &As[buf][wbase]);
    gl_lds16(A + (size_t)(row0 + sa1) * K + k0 + scq * 8,
             &As[buf][2048 + wbase]);
    gl_lds16(Wt + (size_t)(col0 + srow) * K + k0 + scq * 8, &Bs[buf][wbase]);
    gl_lds16(Wt + (size_t)(col0 + 64 + srow) * K + k0 + scq * 8,
             &Bs[buf][2048 + wbase]);
  };

  stage(0, 0);
  int cur = 0;
  for (int k0 = 0; k0 < K; k0 += 32) {
    __syncthreads();
    if (k0 + 32 < K) stage(cur ^ 1, k0 + 32);
    bf16x8 af[4], bg[4];
#pragma unroll
    for (int m = 0; m < 4; m++)
      af[m] = *reinterpret_cast<const bf16x8*>(
          &As[cur][(wr * 64 + m * 16 + (lane & 15)) * 32 + (lane >> 4) * 8]);
#pragma unroll
    for (int n = 0; n < 4; n++)
      bg[n] = *reinterpret_cast<const bf16x8*>(
          &Bs[cur][(wc * 64 + n * 16 + (lane & 15)) * 32 + (lane >> 4) * 8]);
#pragma unroll
    for (int m = 0; m < 4; m++)
#pragma unroll
      for (int n = 0; n < 4; n++)
        acc[m][n] = __builtin_amdgcn_mfma_f32_16x16x32_bf16(af[m], bg[n],
                                                            acc[m][n], 0, 0, 0);
    cur ^= 1;
  }

  if (EPI != 0) {
    const float scale = (EPI == 1) ? ((zb == 0) ? (1.f / (float)L_)
                                                : (2.f / (float)L_))
                                   : (-2.f / (float)L_);
    const int joff = 2 * zb + (EPI == 2 ? 1 : 0);
    bf16* Cb = (bf16*)Cout;
#pragma unroll
    for (int n = 0; n < 4; n++) {
      int col = col0 + wc * 64 + n * 16 + (lane & 15);
#pragma unroll
      for (int m = 0; m < 4; m++) {
#pragma unroll
        for (int j = 0; j < 4; j++) {
          int row = row0 + wr * 64 + m * 16 + (lane >> 4) * 4 + j;
          if (row < M)
            Cb[((size_t)row * N + col) * 64 + joff] =
                __float2bfloat16(acc[m][n][j] * scale);
        }
      }
    }
    return;
  }

  float* Cf = (float*)Cout;
  bf16* Cb = (bf16*)Cout;
  const size_t cbase = (size_t)zb * (size_t)batchC;
#pragma unroll
  for (int n = 0; n < 4; n++) {
    int col = col0 + wc * 64 + n * 16 + (lane & 15);
    float bs = 0.f;
    if (BIAS) bs = bias[col];
#pragma unroll
    for (int m = 0; m < 4; m++) {
#pragma unroll
      for (int j = 0; j < 4; j++) {
        int row = row0 + wr * 64 + m * 16 + (lane >> 4) * 4 + j;
        if (MGUARD && row >= M) continue;
        float v = acc[m][n][j] + bs;
        size_t idx = cbase + (size_t)row * ldc + coff + col;
        if (OUTBF) Cb[idx] = __float2bfloat16(v);
        else Cf[idx] = v;
      }
    }
  }
}

// ---------------------------------------------------------------------------
// Stage B: forward DFT on 32 kept modes, partial over l-chunks of 256.
// ---------------------------------------------------------------------------
__global__ __launch_bounds__(256) void stageB(
    const bf16* __restrict__ q, const float* __restrict__ TwP,
    float* __restrict__ XFp_r, float* __restrict__ XFp_i) {
  __shared__ __align__(16) float Tls[4 * 128 * 16];   // 32 KB
  const int b = blockIdx.x, ig = blockIdx.y, lc = blockIdx.z;
  const int t = threadIdx.x, lane = t & 63, mg = t >> 6;
  const int i0 = ig * 64;
  float ar[8], ai[8];
#pragma unroll
  for (int k = 0; k < 8; k++) { ar[k] = 0.f; ai[k] = 0.f; }
  float* TlsW = &Tls[mg * 2048];

  for (int h = 0; h < 2; h++) {
    const int hb = lc * 256 + h * 128;
#pragma unroll
    for (int s = 0; s < 8; s++) {
      int flat = s * 64 + lane;            // 0..511
      int l = flat >> 2, q4 = flat & 3;
      gl_lds16(TwP + ((size_t)(hb + l) * 4 + mg) * 16 + q4 * 4,
               TlsW + s * 256);
    }
    __syncthreads();
#pragma unroll 4
    for (int l = 0; l < 128; l++) {
      float qv = __bfloat162float(q[((size_t)b * L_ + hb + l) * D_ + i0 + lane]);
      const float* Tp = TlsW + l * 16;
      float4 c0 = *(const float4*)(Tp);
      float4 c1 = *(const float4*)(Tp + 4);
      float4 s0 = *(const float4*)(Tp + 8);
      float4 s1 = *(const float4*)(Tp + 12);
      ar[0] += qv * c0.x; ar[1] += qv * c0.y; ar[2] += qv * c0.z; ar[3] += qv * c0.w;
      ar[4] += qv * c1.x; ar[5] += qv * c1.y; ar[6] += qv * c1.z; ar[7] += qv * c1.w;
      ai[0] += qv * s0.x; ai[1] += qv * s0.y; ai[2] += qv * s0.z; ai[3] += qv * s0.w;
      ai[4] += qv * s1.x; ai[5] += qv * s1.y; ai[6] += qv * s1.z; ai[7] += qv * s1.w;
    }
    __syncthreads();
  }
  size_t base = (((size_t)lc * B_ + b) * D_ + i0 + lane) * 32 + mg * 8;
  float4 r0 = {ar[0], ar[1], ar[2], ar[3]}, r1 = {ar[4], ar[5], ar[6], ar[7]};
  float4 i0v = {ai[0], ai[1], ai[2], ai[3]}, i1v = {ai[4], ai[5], ai[6], ai[7]};
  *(float4*)(XFp_r + base) = r0;
  *(float4*)(XFp_r + base + 4) = r1;
  *(float4*)(XFp_i + base) = i0v;
  *(float4*)(XFp_i + base + 4) = i1v;
}

// ---------------------------------------------------------------------------
// Reduce partials and emit packed bf16 A-operands for the CC GEMMs.
// ---------------------------------------------------------------------------
__global__ __launch_bounds__(256) void reduceXFT(
    const float* __restrict__ XFp_r, const float* __restrict__ XFp_i,
    bf16* __restrict__ Aneg, bf16* __restrict__ Aswap) {
  __shared__ float smr[64][33], smi[64][33];
  const int b = blockIdx.x, ic = blockIdx.y;
  const int i0 = ic * 64;
  const size_t CS = (size_t)B_ * D_ * 32;
#pragma unroll
  for (int s = 0; s < 8; s++) {
    int flat = s * 256 + threadIdx.x;       // 2048 = 64 i x 32 m
    int i = flat >> 5, m = flat & 31;
    size_t e = ((size_t)b * D_ + i0 + i) * 32 + m;
    float sr = 0.f, si = 0.f;
#pragma unroll
    for (int c = 0; c < 8; c++) { sr += XFp_r[c * CS + e]; si += XFp_i[c * CS + e]; }
    smr[i][m] = sr;
    smi[i][m] = si;
  }
  __syncthreads();
#pragma unroll
  for (int s = 0; s < 8; s++) {
    int flat = s * 256 + threadIdx.x;
    int m = flat >> 6, i = flat & 63;
    float sr = smr[i][m], si = smi[i][m];
    size_t base = ((size_t)m * B_ + b) * 1024;
    Aneg[base + i0 + i] = __float2bfloat16(sr);
    Aneg[base + 512 + i0 + i] = __float2bfloat16(-si);
    Aswap[base + i0 + i] = __float2bfloat16(si);
    Aswap[base + 512 + i0 + i] = __float2bfloat16(sr);
  }
}

// ---------------------------------------------------------------------------
// Stage E: u = x - movavg(x)  (rolling window, replicate pad 64/63), bf16 out.
// grid (B, 2, 16): 1024 blocks; 128 l per block.
// ---------------------------------------------------------------------------
__global__ __launch_bounds__(256) void stageE(const float* __restrict__ in,
                                              bf16* __restrict__ outbf) {
  const int b = blockIdx.x, dg = blockIdx.y, lc = blockIdx.z;
  const int d = dg * 256 + threadIdx.x;
  const float* col = in + (size_t)b * L_ * D_ + d;
  bf16* bcol = outbf + (size_t)b * L_ * D_ + d;
  const int l0 = lc * 128;
  float Wsum = 0.f;
  for (int s = l0 - 64; s < l0 + 64; s++) {
    int cl = min(max(s, 0), L_ - 1);
    Wsum += col[(size_t)cl * D_];
  }
  for (int l = l0; l < l0 + 128; l++) {
    float v = col[(size_t)l * D_];
    bcol[(size_t)l * D_] = __float2bfloat16(v - Wsum * (1.f / 128.f));
    int fa = min(l + 64, L_ - 1);
    int fb = max(l - 64, 0);
    Wsum += col[(size_t)fa * D_] - col[(size_t)fb * D_];
  }
}

// ---------------------------------------------------------------------------
// BatchNorm over (b, d) per time step l — res read as bf16.
// ---------------------------------------------------------------------------
__global__ __launch_bounds__(256) void bnStats(const ushort* __restrict__ res,
                                               float* __restrict__ meanb,
                                               float* __restrict__ rstdb) {
  const int l = blockIdx.x;
  const int t = threadIdx.x;
  float s = 0.f, s2 = 0.f;
  for (int b = 0; b < B_; b++) {
    const ushort* p = res + ((size_t)b * L_ + l) * D_ + 2 * t;
    ushort2 v2 = *(const ushort2*)p;
    float a = b2f(v2.x), c = b2f(v2.y);
    s += a + c;
    s2 += a * a + c * c;
  }
#pragma unroll
  for (int off = 32; off > 0; off >>= 1) {
    s += __shfl_down(s, off, 64);
    s2 += __shfl_down(s2, off, 64);
  }
  __shared__ float shs[4], shs2[4];
  int wid = t >> 6;
  if ((t & 63) == 0) { shs[wid] = s; shs2[wid] = s2; }
  __syncthreads();
  if (t == 0) {
    float S = shs[0] + shs[1] + shs[2] + shs[3];
    float S2 = shs2[0] + shs2[1] + shs2[2] + shs2[3];
    const float inv = 1.f / (float)(B_ * D_);
    float mean = S * inv;
    float var = S2 * inv - mean * mean;
    meanb[l] = mean;
    rstdb[l] = rsqrtf(var + 1e-5f);
  }
}

__global__ __launch_bounds__(256) void bnApply(
    const ushort* __restrict__ res, const float* __restrict__ gamma,
    const float* __restrict__ beta, const float* __restrict__ meanb,
    const float* __restrict__ rstdb, float* __restrict__ out) {
  size_t idx = (size_t)blockIdx.x * 256 + threadIdx.x;   // 4-elem index
  if (idx >= NBIG / 4) return;
  size_t e = idx * 4;
  int l = (int)((e >> 9) & (L_ - 1));
  ushort4 v = *(const ushort4*)(res + e);
  float m = meanb[l], rs = rstdb[l];
  float g = gamma[l] * rs, bt = beta[l];
  float4 o;
  o.x = (b2f(v.x) - m) * g + bt;
  o.y = (b2f(v.y) - m) * g + bt;
  o.z = (b2f(v.z) - m) * g + bt;
  o.w = (b2f(v.w) - m) * g + bt;
  *(float4*)(out + e) = o;
}

// ---------------------------------------------------------------------------
extern "C" void kernel_launch(void* const* d_in, const int* in_sizes, int n_in,
                              void* d_out, int out_size, void* d_ws,
                              size_t ws_size, hipStream_t stream) {
  const float* x      = (const float*)d_in[0];
  const float* W_in   = (const float*)d_in[1];
  const float* b_in   = (const float*)d_in[2];
  const float* Wf_r   = (const float*)d_in[3];
  const float* Wf_i   = (const float*)d_in[4];
  const float* W_out  = (const float*)d_in[5];
  const float* b_out  = (const float*)d_in[6];  // cancels in decomposition
  const float* W_c1   = (const float*)d_in[7];
  const float* W_c2   = (const float*)d_in[8];
  const float* gamma  = (const float*)d_in[9];
  const float* beta   = (const float*)d_in[10];
  float* outp = (float*)d_out;
  (void)b_out;

  // ---- workspace layout ----
  float* f = (float*)d_ws;
  float* buf0 = f;                                   // NBIG region
  bf16*  resbf = (bf16*)buf0;                        // res as bf16 (F2 out)
  // aliases inside buf0 (all dead before F2 writes res):
  float* XFp_r = buf0;                               // 8*524288 f
  float* XFp_i = XFp_r + (size_t)8 * 524288;         // 8*524288 f
  bf16*  WfmR  = (bf16*)(XFp_i + (size_t)8 * 524288);// 8388608 bf16
  bf16*  WfmI  = WfmR + (size_t)8388608;             // 8388608 bf16
  bf16*  Woutbf= WfmI + (size_t)8388608;             // 262144 bf16
  bf16*  Wcat  = Woutbf + 262144;                    // 32*512*1024 bf16
  bf16*  Aneg  = Wcat + (size_t)32 * 512 * 1024;     // 1048576 bf16
  bf16*  Aswap = Aneg + 1048576;                     // 1048576 bf16
  bf16*  CCT   = Aswap + 1048576;                    // 32*512*64 bf16
  // tail after buf0:
  float* TwP   = f + NBIG;                           // 131072 f
  float* TbF   = TwP + 131072;                       // 131072 f
  bf16*  TbD   = (bf16*)(TbF + 131072);              // 131072 bf16
  bf16*  Wibf  = TbD + 131072;                       // 262144 bf16 x3
  bf16*  W1bf  = Wibf + 262144;
  bf16*  W2bf  = W1bf + 262144;
  float* meanb = (float*)(W2bf + 262144);
  float* rstdb = meanb + L_;

  // d_out double-duty: [ - |qbf] -> [ - |ubf] -> [xrbf|ubf] -> [xrbf|y1bf]
  bf16* qbf  = ((bf16*)d_out) + NBIG;
  bf16* ubf  = qbf;                 // alias: qbf dead after stageB
  bf16* xrbf = (bf16*)d_out;        // 1st half: free until gemmD writes it
  bf16* y1bf = qbf;                 // alias: ubf dead after gemmD

  // tables + dtype conversions (weights only — x is consumed fp32 directly)
  genTwP<<<512, 256, 0, stream>>>(TwP);
  genTbF<<<512, 256, 0, stream>>>(TbF);
  genTbDbf<<<512, 256, 0, stream>>>(TbF, TbD);
  f2bfK<<<256, 256, 0, stream>>>((const float4*)W_in, (ushort4*)Wibf, 65536);
  f2bfK<<<256, 256, 0, stream>>>((const float4*)W_c1, (ushort4*)W1bf, 65536);
  f2bfK<<<256, 256, 0, stream>>>((const float4*)W_c2, (ushort4*)W2bf, 65536);
  f2bfK<<<256, 256, 0, stream>>>((const float4*)W_out, (ushort4*)Woutbf, 65536);
  twWf<<<4096, 256, 0, stream>>>(Wf_r, Wf_i, WfmR, WfmI);

  // fold W_out into Wf -> Wcat[m][d][0:512]=R, [512:1024]=I  (batchC = slice)
  gemm_bt<false, true, false, 0><<<dim3(4, 4, 32), 256, 0, stream>>>(
      Woutbf, WfmR, nullptr, Wcat, 512, 512, 512, 0, 262144, 524288, 1024, 0);
  gemm_bt<false, true, false, 0><<<dim3(4, 4, 32), 256, 0, stream>>>(
      Woutbf, WfmI, nullptr, Wcat, 512, 512, 512, 0, 262144, 524288, 1024, 512);

  // A: q = x @ W_in^T + b_in  (fp32 A reg-staged in-kernel; bf16 out)
  gemm_k64<false, false, true, true, false, true><<<2048, 256, 0, stream>>>(
      x, Wibf, b_in, nullptr, qbf, BLROWS, D_, D_);

  // B: forward DFT partials + reduce/pack
  stageB<<<dim3(B_, 8, 8), 256, 0, stream>>>(qbf, TwP, XFp_r, XFp_i);
  reduceXFT<<<dim3(B_, 8), 256, 0, stream>>>(XFp_r, XFp_i, Aneg, Aswap);

  // CC GEMMs: Re(G), Im(G) -> scaled bf16 CCT[b][d][64]
  gemm_bt<false, false, true, 1><<<dim3(1, 4, 32), 256, 0, stream>>>(
      Aneg, Wcat, nullptr, CCT, 32, 512, 1024, 32768, 524288, 0, 0, 0);
  gemm_bt<false, false, true, 2><<<dim3(1, 4, 32), 256, 0, stream>>>(
      Aswap, Wcat, nullptr, CCT, 32, 512, 1024, 32768, 524288, 0, 0, 0);

  // E: u = x - MA(x) -> ubf (2nd half; qbf dead)  [1024 blocks]
  stageE<<<dim3(B_, 2, 16), 256, 0, stream>>>(x, ubf);

  // D: xr = u + TbD @ CCT^T  -> xrbf (1st half)
  gemmD<<<dim3(16, 4, 32), 256, 0, stream>>>(TbD, CCT, (const ushort*)ubf,
                                             (ushort*)xrbf);

  // F1: y1 = gelu(xr @ Wc1^T)  (bf16 out -> 2nd half; ubf dead)
  gemm_k64<true, false, false, true, false, false><<<2048, 256, 0, stream>>>(
      xrbf, W1bf, nullptr, nullptr, y1bf, BLROWS, D_, D_);

  // F2: res = xr + y1 @ Wc2^T  (bf16 -> resbf in buf0; resid read as bf16)
  gemm_k64<false, true, false, true, true, false><<<2048, 256, 0, stream>>>(
      y1bf, W2bf, nullptr, xrbf, resbf, BLROWS, D_, D_);

  // G: BatchNorm over (b, d) per l  (res read as bf16)
  bnStats<<<L_, 256, 0, stream>>>((const ushort*)resbf, meanb, rstdb);
  bnApply<<<(NBIG / 4 + 255) / 256, 256, 0, stream>>>(
      (const ushort*)resbf, gamma, beta, meanb, rstdb, outp);
}

// Round 14
// 685.326 us; speedup vs baseline: 1.1399x; 1.1399x over previous
//
#include <hip/hip_runtime.h>
#include <hip/hip_bf16.h>
#include <math.h>

#define B_   32
#define L_   2048
#define D_   512
#define BLROWS (B_*L_)                 // 65536
#define NBIG ((size_t)BLROWS * D_)     // 33554432

typedef __hip_bfloat16 bf16;
using bf16x8 = __attribute__((ext_vector_type(8))) short;
using f32x4  = __attribute__((ext_vector_type(4))) float;

__device__ __forceinline__ unsigned short f2b(float f) {
  bf16 h = __float2bfloat16(f);
  return *reinterpret_cast<unsigned short*>(&h);
}
__device__ __forceinline__ float b2f(unsigned short u) {
  union { unsigned int i; float f; } c;
  c.i = ((unsigned int)u) << 16;
  return c.f;
}

__device__ __forceinline__ void gl_lds16(const void* g, void* l) {
  __builtin_amdgcn_global_load_lds(
      (const __attribute__((address_space(1))) void*)g,
      (__attribute__((address_space(3))) void*)l, 16, 0, 0);
}

// ---------------------------------------------------------------------------
// fp32 -> bf16 vectorized converter (weights only)
// ---------------------------------------------------------------------------
__global__ __launch_bounds__(256) void f2bfK(const float4* __restrict__ src,
                                             ushort4* __restrict__ dst,
                                             size_t n4) {
  for (size_t i = (size_t)blockIdx.x * 256 + threadIdx.x; i < n4;
       i += (size_t)gridDim.x * 256) {
    float4 v = src[i];
    ushort4 o;
    o.x = f2b(v.x); o.y = f2b(v.y); o.z = f2b(v.z); o.w = f2b(v.w);
    dst[i] = o;
  }
}

// ---------------------------------------------------------------------------
// Twiddle tables.
// ---------------------------------------------------------------------------
__global__ __launch_bounds__(256) void genTwP(float* __restrict__ TwP) {
  int idx = blockIdx.x * 256 + threadIdx.x;   // l*64 + mg*16 + j ; 131072
  int l = idx >> 6, rem = idx & 63, mg = rem >> 4, j = rem & 15;
  int m = mg * 8 + (j & 7);
  int r = (m * l) & (L_ - 1);
  float ang = (float)r * (6.283185307179586f / (float)L_);
  TwP[idx] = (j < 8) ? cosf(ang) : -sinf(ang);
}

__global__ __launch_bounds__(256) void genTbF(float* __restrict__ Tb) {
  int idx = blockIdx.x * 256 + threadIdx.x;   // l*64 + j ; 131072
  int l = idx >> 6, j = idx & 63;
  int m = j >> 1;
  int r = (m * l) & (L_ - 1);
  float ang = (float)r * (6.283185307179586f / (float)L_);
  Tb[idx] = (j & 1) ? sinf(ang) : cosf(ang);
}

// TbD = Tb - movavg_l(Tb), emitted as bf16 (decomposed inverse basis)
__global__ __launch_bounds__(256) void genTbDbf(const float* __restrict__ Tb,
                                                bf16* __restrict__ TbD) {
  int idx = blockIdx.x * 256 + threadIdx.x;   // l*64 + j ; 131072
  int l = idx >> 6, j = idx & 63;
  float s = 0.f;
  for (int t = l - 64; t < l + 64; t++) {
    int cl = min(max(t, 0), L_ - 1);
    s += Tb[cl * 64 + j];
  }
  TbD[idx] = __float2bfloat16(Tb[idx] - s * (1.f / 128.f));
}

// ---------------------------------------------------------------------------
// twWf2: Wf_{r,i}[i][o][m] fp32 -> Wcat2[m][o][k] bf16,
//        k<512 -> Wf_r[i=k][o][m], k>=512 -> Wf_i[k-512][o][m].
// grid (ib=8, ob=64, arr=2), 256 thr.  Block: 64 i x 8 o x 32 m.
// Read phase: thread t owns om=t (o=t>>5, m=t&31); coalesced global reads
// (lanes consecutive in om); packs 8 i -> b128 LDS write (pad 72 keeps 16B
// alignment).  Write phase: 8 passes; each thread emits one 16B chunk of a
// 128B-contiguous [m][o][i] run.
// ---------------------------------------------------------------------------
__global__ __launch_bounds__(256) void twWf2(const float* __restrict__ Wfr,
                                             const float* __restrict__ Wfi,
                                             bf16* __restrict__ Wcat2) {
  __shared__ __align__(16) bf16 st[256 * 72];   // [om][i] padded, 36 KB
  const int t = threadIdx.x;
  const int i0 = blockIdx.x * 64, o0 = blockIdx.y * 8;
  const int arr = blockIdx.z;
  const float* src = arr ? Wfi : Wfr;
#pragma unroll
  for (int s8 = 0; s8 < 8; s8++) {
    unsigned short v[8];
#pragma unroll
    for (int ss = 0; ss < 8; ss++)
      v[ss] = f2b(src[(size_t)(i0 + s8 * 8 + ss) * 16384 + o0 * 32 + t]);
    int4 wv;
    wv.x = (int)v[0] | ((int)v[1] << 16);
    wv.y = (int)v[2] | ((int)v[3] << 16);
    wv.z = (int)v[4] | ((int)v[5] << 16);
    wv.w = (int)v[6] | ((int)v[7] << 16);
    *(int4*)&st[t * 72 + s8 * 8] = wv;
  }
  __syncthreads();
#pragma unroll
  for (int p = 0; p < 8; p++) {
    const int om = p * 32 + (t >> 3), c = t & 7;
    const int o = om >> 5, m = om & 31;
    int4 rv = *(const int4*)&st[om * 72 + c * 8];
    bf16* dst = Wcat2 + (size_t)m * 524288 + (size_t)(o0 + o) * 1024 +
                arr * 512 + i0 + c * 8;
    *(int4*)dst = rv;
  }
}

// ---------------------------------------------------------------------------
// gemm_k64 (R12 form, reinstated): 128x128 tile, BK=64, 2-buf __syncthreads
// pipeline, XOR-swizzled LDS for BOTH operands (R11/R12-verified: conflicts 0),
// B staged via gl_lds (R13's B-direct regressed: bg loads serialized on the
// K-step critical path).  AFP32: A read fp32, reg-staged cvt+ds_write_b128.
// Transposed MFMA (C^T = mfma(B,A)) -> d-major vectorized epilogue.
// Grid 2048 1-D; XCD-pairing decode for A-panel L2 reuse.
// ---------------------------------------------------------------------------
template <bool GELU, bool RESID, bool BIAS, bool OUTBF, bool RESBF, bool AFP32>
__global__ __launch_bounds__(256) void gemm_k64(
    const void* __restrict__ Av, const bf16* __restrict__ Wt,
    const float* __restrict__ bias, const void* __restrict__ resid,
    void* __restrict__ Cout, int M, int N, int K) {
  __shared__ __align__(16) bf16 As[2][128 * 64];   // 16 KB each
  __shared__ __align__(16) bf16 Bs[2][128 * 64];
  const int t = threadIdx.x;
  const int lane = t & 63;
  const int w = t >> 6, wr = w >> 1, wc = w & 1;

  const int id = blockIdx.x;
  const int xcd = id & 7, rest = id >> 3;
  const int cb = rest & 3, rg = rest >> 2;
  const int row0 = (rg * 8 + xcd) * 128, col0 = cb * 128;

  const bf16* Ab = (const bf16*)Av;
  const float* Af = (const float*)Av;

  f32x4 acc[4][4];   // acc[n][m] = C^T fragment
#pragma unroll
  for (int i = 0; i < 4; i++)
#pragma unroll
    for (int j = 0; j < 4; j++) acc[i][j] = (f32x4){0.f, 0.f, 0.f, 0.f};

  auto stage = [&](int buf, int k0) {
#pragma unroll
    for (int s = 0; s < 4; s++) {
      const int ci = s * 256 + t;
      const int row = ci >> 3;
      const int cg = ci & 7;
      const int pc = cg ^ (row & 7);
      if (AFP32) {
        const float* ax = Af + (size_t)(row0 + row) * K + k0 + cg * 8;
        float4 v0 = *(const float4*)(ax);
        float4 v1 = *(const float4*)(ax + 4);
        int4 wv;
        wv.x = (int)f2b(v0.x) | ((int)f2b(v0.y) << 16);
        wv.y = (int)f2b(v0.z) | ((int)f2b(v0.w) << 16);
        wv.z = (int)f2b(v1.x) | ((int)f2b(v1.y) << 16);
        wv.w = (int)f2b(v1.z) | ((int)f2b(v1.w) << 16);
        *(int4*)&As[buf][(size_t)(row * 8 + pc) * 8] = wv;
      } else {
        const int kqg = cg ^ (row & 7);
        bf16* dA = &As[buf][(size_t)(s * 256 + (t & ~63)) * 8];
        gl_lds16(Ab + (size_t)(row0 + row) * K + k0 + kqg * 8, dA);
      }
      {
        const int kqg = cg ^ (row & 7);
        bf16* dB = &Bs[buf][(size_t)(s * 256 + (t & ~63)) * 8];
        gl_lds16(Wt + (size_t)(col0 + row) * K + k0 + kqg * 8, dB);
      }
    }
  };

  stage(0, 0);
  int cur = 0;
  for (int k0 = 0; k0 < K; k0 += 64) {
    __syncthreads();                   // drains stage(cur); prev reads done
    if (k0 + 64 < K) stage(cur ^ 1, k0 + 64);
#pragma unroll
    for (int ks = 0; ks < 2; ks++) {
      const int c = ks * 4 + (lane >> 4);        // global k-chunk
      const int pc = c ^ (lane & 7);             // phys (swizzled) chunk
      bf16x8 af[4], bg[4];
#pragma unroll
      for (int m = 0; m < 4; m++) {
        const int ra = wr * 64 + m * 16 + (lane & 15);
        af[m] = *reinterpret_cast<const bf16x8*>(&As[cur][(ra * 8 + pc) * 8]);
      }
#pragma unroll
      for (int n = 0; n < 4; n++) {
        const int rb = wc * 64 + n * 16 + (lane & 15);
        bg[n] = *reinterpret_cast<const bf16x8*>(&Bs[cur][(rb * 8 + pc) * 8]);
      }
#pragma unroll
      for (int n = 0; n < 4; n++)
#pragma unroll
        for (int m = 0; m < 4; m++)
          acc[n][m] = __builtin_amdgcn_mfma_f32_16x16x32_bf16(
              bg[n], af[m], acc[n][m], 0, 0, 0);
    }
    cur ^= 1;
  }

  // transposed epilogue: d-major vector access
  float* Cf = (float*)Cout;
  ushort* Cb = (ushort*)Cout;
#pragma unroll
  for (int n = 0; n < 4; n++) {
    const int dbase = col0 + wc * 64 + n * 16 + ((lane >> 4) << 2);
    float4 bsv = {0.f, 0.f, 0.f, 0.f};
    if (BIAS) bsv = *(const float4*)(bias + dbase);
#pragma unroll
    for (int m = 0; m < 4; m++) {
      const size_t r = (size_t)row0 + wr * 64 + m * 16 + (lane & 15);
      float v[4];
#pragma unroll
      for (int j = 0; j < 4; j++) {
        float u = acc[n][m][j] + (BIAS ? (&bsv.x)[j] : 0.f);
        if (GELU) u = 0.5f * u * (1.0f + erff(u * 0.70710678118654752f));
        v[j] = u;
      }
      if (RESID) {
        if (RESBF) {
          ushort4 rv = *(const ushort4*)((const ushort*)resid + r * N + dbase);
          v[0] += b2f(rv.x); v[1] += b2f(rv.y);
          v[2] += b2f(rv.z); v[3] += b2f(rv.w);
        } else {
          float4 rv = *(const float4*)((const float*)resid + r * N + dbase);
          v[0] += rv.x; v[1] += rv.y; v[2] += rv.z; v[3] += rv.w;
        }
      }
      if (OUTBF) {
        ushort4 o = {f2b(v[0]), f2b(v[1]), f2b(v[2]), f2b(v[3])};
        *(ushort4*)(Cb + r * N + dbase) = o;
      } else {
        float4 o = {v[0], v[1], v[2], v[3]};
        *(float4*)(Cf + r * N + dbase) = o;
      }
    }
  }
}

// ---------------------------------------------------------------------------
// gemmD: xr[b][l][d] = u[b][l][d] + sum_j TbD[l][j] * CCT[b][d][j]
// ---------------------------------------------------------------------------
__global__ __launch_bounds__(256) void gemmD(
    const bf16* __restrict__ TbD, const bf16* __restrict__ CCT,
    const ushort* __restrict__ u, ushort* __restrict__ xr) {
  __shared__ __align__(16) bf16 As[128 * 64];
  __shared__ __align__(16) bf16 Bs[128 * 64];
  const int t = threadIdx.x;
  const int lane = t & 63;
  const int wid = t >> 6, wr = wid >> 1, wc = wid & 1;
  const int row0 = blockIdx.x * 128, col0 = blockIdx.y * 128;
  const int b = blockIdx.z;
  const bf16* Bsrc = CCT + (size_t)b * 512 * 64;

  const int srow = t >> 3, schk = t & 7;
  const int wb16 = (t & ~63) * 8;
#pragma unroll
  for (int p = 0; p < 4; p++) {
    gl_lds16(TbD + (size_t)(row0 + srow + 32 * p) * 64 + schk * 8,
             &As[p * 2048 + wb16]);
    gl_lds16(Bsrc + (size_t)(col0 + srow + 32 * p) * 64 + schk * 8,
             &Bs[p * 2048 + wb16]);
  }
  __syncthreads();

  f32x4 acc[4][4];
#pragma unroll
  for (int i = 0; i < 4; i++)
#pragma unroll
    for (int j = 0; j < 4; j++) acc[i][j] = (f32x4){0.f, 0.f, 0.f, 0.f};

#pragma unroll
  for (int ks = 0; ks < 2; ks++) {
    bf16x8 af[4], bg[4];
#pragma unroll
    for (int m = 0; m < 4; m++)
      af[m] = *reinterpret_cast<const bf16x8*>(
          &As[(wr * 64 + m * 16 + (lane & 15)) * 64 + ks * 32 +
              (lane >> 4) * 8]);
#pragma unroll
    for (int n = 0; n < 4; n++)
      bg[n] = *reinterpret_cast<const bf16x8*>(
          &Bs[(wc * 64 + n * 16 + (lane & 15)) * 64 + ks * 32 +
              (lane >> 4) * 8]);
#pragma unroll
    for (int n = 0; n < 4; n++)
#pragma unroll
      for (int m = 0; m < 4; m++)
        acc[n][m] = __builtin_amdgcn_mfma_f32_16x16x32_bf16(bg[n], af[m],
                                                            acc[n][m], 0, 0, 0);
  }

#pragma unroll
  for (int n = 0; n < 4; n++) {
    const int dbase = col0 + wc * 64 + n * 16 + ((lane >> 4) << 2);
#pragma unroll
    for (int m = 0; m < 4; m++) {
      const int l = row0 + wr * 64 + m * 16 + (lane & 15);
      const size_t rg = ((size_t)b * L_ + l) * D_ + dbase;
      ushort4 uv = *(const ushort4*)(u + rg);
      ushort4 o;
      o.x = f2b(acc[n][m][0] + b2f(uv.x));
      o.y = f2b(acc[n][m][1] + b2f(uv.y));
      o.z = f2b(acc[n][m][2] + b2f(uv.z));
      o.w = f2b(acc[n][m][3] + b2f(uv.w));
      *(ushort4*)(xr + rg) = o;
    }
  }
}

// ---------------------------------------------------------------------------
// gemm_bt (2-buf): OM GEMMs (EPI 0, normal epilogue with batchC/ldc/coff)
// and G GEMMs (EPI 3 = CCT real write, EPI 4 = CCT imag write).
// G epilogue: row = b*32+m (M=1024); CCT[(b*512+col)*64 + 2m (+1)] = scale*acc.
// ---------------------------------------------------------------------------
template <bool BIAS, bool OUTBF, bool MGUARD, int EPI>
__global__ __launch_bounds__(256) void gemm_bt(
    const bf16* __restrict__ A, const bf16* __restrict__ Wt,
    const float* __restrict__ bias, void* __restrict__ Cout,
    int M, int N, int K, long batchA, long batchB, long batchC,
    int ldc, int coff) {
  __shared__ __align__(16) bf16 As[2][128 * 32];
  __shared__ __align__(16) bf16 Bs[2][128 * 32];
  const int t = threadIdx.x;
  const int lane = t & 63;
  const int wid = t >> 6, wr = wid >> 1, wc = wid & 1;
  const int row0 = blockIdx.x * 128, col0 = blockIdx.y * 128;
  const int zb = blockIdx.z;
  A += (size_t)zb * (size_t)batchA;
  Wt += (size_t)zb * (size_t)batchB;

  f32x4 acc[4][4];
#pragma unroll
  for (int i = 0; i < 4; i++)
#pragma unroll
    for (int j = 0; j < 4; j++) acc[i][j] = (f32x4){0.f, 0.f, 0.f, 0.f};

  const int srow = t >> 2, scq = t & 3;
  const int sa0 = MGUARD ? (srow & 31) : srow;
  const int sa1 = MGUARD ? (srow & 31) : (64 + srow);
  const int wbase = (t & ~63) * 8;

  auto stage = [&](int buf, int k0) {
    gl_lds16(A + (size_t)(row0 + sa0) * K + k0 + scq * 8, &As[buf][wbase]);
    gl_lds16(A + (size_t)(row0 + sa1) * K + k0 + scq * 8,
             &As[buf][2048 + wbase]);
    gl_lds16(Wt + (size_t)(col0 + srow) * K + k0 + scq * 8, &Bs[buf][wbase]);
    gl_lds16(Wt + (size_t)(col0 + 64 + srow) * K + k0 + scq * 8,
             &Bs[buf][2048 + wbase]);
  };

  stage(0, 0);
  int cur = 0;
  for (int k0 = 0; k0 < K; k0 += 32) {
    __syncthreads();
    if (k0 + 32 < K) stage(cur ^ 1, k0 + 32);
    bf16x8 af[4], bg[4];
#pragma unroll
    for (int m = 0; m < 4; m++)
      af[m] = *reinterpret_cast<const bf16x8*>(
          &As[cur][(wr * 64 + m * 16 + (lane & 15)) * 32 + (lane >> 4) * 8]);
#pragma unroll
    for (int n = 0; n < 4; n++)
      bg[n] = *reinterpret_cast<const bf16x8*>(
          &Bs[cur][(wc * 64 + n * 16 + (lane & 15)) * 32 + (lane >> 4) * 8]);
#pragma unroll
    for (int m = 0; m < 4; m++)
#pragma unroll
      for (int n = 0; n < 4; n++)
        acc[m][n] = __builtin_amdgcn_mfma_f32_16x16x32_bf16(af[m], bg[n],
                                                            acc[m][n], 0, 0, 0);
    cur ^= 1;
  }

  if (EPI == 3 || EPI == 4) {
    bf16* Cb = (bf16*)Cout;
#pragma unroll
    for (int n = 0; n < 4; n++) {
      int col = col0 + wc * 64 + n * 16 + (lane & 15);
#pragma unroll
      for (int m = 0; m < 4; m++) {
#pragma unroll
        for (int j = 0; j < 4; j++) {
          int row = row0 + wr * 64 + m * 16 + (lane >> 4) * 4 + j;
          int bb = row >> 5, mm = row & 31;
          float scale = (EPI == 3)
              ? ((mm == 0) ? (1.f / (float)L_) : (2.f / (float)L_))
              : (-2.f / (float)L_);
          Cb[((size_t)bb * 512 + col) * 64 + 2 * mm + (EPI == 4 ? 1 : 0)] =
              __float2bfloat16(acc[m][n][j] * scale);
        }
      }
    }
    return;
  }

  float* Cf = (float*)Cout;
  bf16* Cb = (bf16*)Cout;
  const size_t cbase = (size_t)zb * (size_t)batchC;
#pragma unroll
  for (int n = 0; n < 4; n++) {
    int col = col0 + wc * 64 + n * 16 + (lane & 15);
    float bs = 0.f;
    if (BIAS) bs = bias[col];
#pragma unroll
    for (int m = 0; m < 4; m++) {
#pragma unroll
      for (int j = 0; j < 4; j++) {
        int row = row0 + wr * 64 + m * 16 + (lane >> 4) * 4 + j;
        if (MGUARD && row >= M) continue;
        float v = acc[m][n][j] + bs;
        size_t idx = cbase + (size_t)row * ldc + coff + col;
        if (OUTBF) Cb[idx] = __float2bfloat16(v);
        else Cf[idx] = v;
      }
    }
  }
}

// ---------------------------------------------------------------------------
// Stage B: forward DFT on 32 kept modes, partial over l-chunks of 256.
// ---------------------------------------------------------------------------
__global__ __launch_bounds__(256) void stageB(
    const bf16* __restrict__ q, const float* __restrict__ TwP,
    float* __restrict__ XFp_r, float* __restrict__ XFp_i) {
  __shared__ __align__(16) float Tls[4 * 128 * 16];   // 32 KB
  const int b = blockIdx.x, ig = blockIdx.y, lc = blockIdx.z;
  const int t = threadIdx.x, lane = t & 63, mg = t >> 6;
  const int i0 = ig * 64;
  float ar[8], ai[8];
#pragma unroll
  for (int k = 0; k < 8; k++) { ar[k] = 0.f; ai[k] = 0.f; }
  float* TlsW = &Tls[mg * 2048];

  for (int h = 0; h < 2; h++) {
    const int hb = lc * 256 + h * 128;
#pragma unroll
    for (int s = 0; s < 8; s++) {
      int flat = s * 64 + lane;            // 0..511
      int l = flat >> 2, q4 = flat & 3;
      gl_lds16(TwP + ((size_t)(hb + l) * 4 + mg) * 16 + q4 * 4,
               TlsW + s * 256);
    }
    __syncthreads();
#pragma unroll 4
    for (int l = 0; l < 128; l++) {
      float qv = __bfloat162float(q[((size_t)b * L_ + hb + l) * D_ + i0 + lane]);
      const float* Tp = TlsW + l * 16;
      float4 c0 = *(const float4*)(Tp);
      float4 c1 = *(const float4*)(Tp + 4);
      float4 s0 = *(const float4*)(Tp + 8);
      float4 s1 = *(const float4*)(Tp + 12);
      ar[0] += qv * c0.x; ar[1] += qv * c0.y; ar[2] += qv * c0.z; ar[3] += qv * c0.w;
      ar[4] += qv * c1.x; ar[5] += qv * c1.y; ar[6] += qv * c1.z; ar[7] += qv * c1.w;
      ai[0] += qv * s0.x; ai[1] += qv * s0.y; ai[2] += qv * s0.z; ai[3] += qv * s0.w;
      ai[4] += qv * s1.x; ai[5] += qv * s1.y; ai[6] += qv * s1.z; ai[7] += qv * s1.w;
    }
    __syncthreads();
  }
  size_t base = (((size_t)lc * B_ + b) * D_ + i0 + lane) * 32 + mg * 8;
  float4 r0 = {ar[0], ar[1], ar[2], ar[3]}, r1 = {ar[4], ar[5], ar[6], ar[7]};
  float4 i0v = {ai[0], ai[1], ai[2], ai[3]}, i1v = {ai[4], ai[5], ai[6], ai[7]};
  *(float4*)(XFp_r + base) = r0;
  *(float4*)(XFp_r + base + 4) = r1;
  *(float4*)(XFp_i + base) = i0v;
  *(float4*)(XFp_i + base + 4) = i1v;
}

// ---------------------------------------------------------------------------
// Reduce partials and emit packed bf16 A-operands for the OM GEMMs.
// ---------------------------------------------------------------------------
__global__ __launch_bounds__(256) void reduceXFT(
    const float* __restrict__ XFp_r, const float* __restrict__ XFp_i,
    bf16* __restrict__ Aneg, bf16* __restrict__ Aswap) {
  __shared__ float smr[64][33], smi[64][33];
  const int b = blockIdx.x, ic = blockIdx.y;
  const int i0 = ic * 64;
  const size_t CS = (size_t)B_ * D_ * 32;
#pragma unroll
  for (int s = 0; s < 8; s++) {
    int flat = s * 256 + threadIdx.x;       // 2048 = 64 i x 32 m
    int i = flat >> 5, m = flat & 31;
    size_t e = ((size_t)b * D_ + i0 + i) * 32 + m;
    float sr = 0.f, si = 0.f;
#pragma unroll
    for (int c = 0; c < 8; c++) { sr += XFp_r[c * CS + e]; si += XFp_i[c * CS + e]; }
    smr[i][m] = sr;
    smi[i][m] = si;
  }
  __syncthreads();
#pragma unroll
  for (int s = 0; s < 8; s++) {
    int flat = s * 256 + threadIdx.x;
    int m = flat >> 6, i = flat & 63;
    float sr = smr[i][m], si = smi[i][m];
    size_t base = ((size_t)m * B_ + b) * 1024;
    Aneg[base + i0 + i] = __float2bfloat16(sr);
    Aneg[base + 512 + i0 + i] = __float2bfloat16(-si);
    Aswap[base + i0 + i] = __float2bfloat16(si);
    Aswap[base + 512 + i0 + i] = __float2bfloat16(sr);
  }
}

// ---------------------------------------------------------------------------
// Stage E: u = x - movavg(x)  (rolling window, replicate pad 64/63), bf16 out.
// ---------------------------------------------------------------------------
__global__ __launch_bounds__(256) void stageE(const float* __restrict__ in,
                                              bf16* __restrict__ outbf) {
  const int b = blockIdx.x, dg = blockIdx.y, lc = blockIdx.z;
  const int d = dg * 256 + threadIdx.x;
  const float* col = in + (size_t)b * L_ * D_ + d;
  bf16* bcol = outbf + (size_t)b * L_ * D_ + d;
  const int l0 = lc * 128;
  float Wsum = 0.f;
  for (int s = l0 - 64; s < l0 + 64; s++) {
    int cl = min(max(s, 0), L_ - 1);
    Wsum += col[(size_t)cl * D_];
  }
  for (int l = l0; l < l0 + 128; l++) {
    float v = col[(size_t)l * D_];
    bcol[(size_t)l * D_] = __float2bfloat16(v - Wsum * (1.f / 128.f));
    int fa = min(l + 64, L_ - 1);
    int fb = max(l - 64, 0);
    Wsum += col[(size_t)fa * D_] - col[(size_t)fb * D_];
  }
}

// ---------------------------------------------------------------------------
// BatchNorm over (b, d) per time step l — res read as bf16.
// ---------------------------------------------------------------------------
__global__ __launch_bounds__(256) void bnStats(const ushort* __restrict__ res,
                                               float* __restrict__ meanb,
                                               float* __restrict__ rstdb) {
  const int l = blockIdx.x;
  const int t = threadIdx.x;
  float s = 0.f, s2 = 0.f;
  for (int b = 0; b < B_; b++) {
    const ushort* p = res + ((size_t)b * L_ + l) * D_ + 2 * t;
    ushort2 v2 = *(const ushort2*)p;
    float a = b2f(v2.x), c = b2f(v2.y);
    s += a + c;
    s2 += a * a + c * c;
  }
#pragma unroll
  for (int off = 32; off > 0; off >>= 1) {
    s += __shfl_down(s, off, 64);
    s2 += __shfl_down(s2, off, 64);
  }
  __shared__ float shs[4], shs2[4];
  int wid = t >> 6;
  if ((t & 63) == 0) { shs[wid] = s; shs2[wid] = s2; }
  __syncthreads();
  if (t == 0) {
    float S = shs[0] + shs[1] + shs[2] + shs[3];
    float S2 = shs2[0] + shs2[1] + shs2[2] + shs2[3];
    const float inv = 1.f / (float)(B_ * D_);
    float mean = S * inv;
    float var = S2 * inv - mean * mean;
    meanb[l] = mean;
    rstdb[l] = rsqrtf(var + 1e-5f);
  }
}

__global__ __launch_bounds__(256) void bnApply(
    const ushort* __restrict__ res, const float* __restrict__ gamma,
    const float* __restrict__ beta, const float* __restrict__ meanb,
    const float* __restrict__ rstdb, float* __restrict__ out) {
  size_t idx = (size_t)blockIdx.x * 256 + threadIdx.x;   // 4-elem index
  if (idx >= NBIG / 4) return;
  size_t e = idx * 4;
  int l = (int)((e >> 9) & (L_ - 1));
  ushort4 v = *(const ushort4*)(res + e);
  float m = meanb[l], rs = rstdb[l];
  float g = gamma[l] * rs, bt = beta[l];
  float4 o;
  o.x = (b2f(v.x) - m) * g + bt;
  o.y = (b2f(v.y) - m) * g + bt;
  o.z = (b2f(v.z) - m) * g + bt;
  o.w = (b2f(v.w) - m) * g + bt;
  *(float4*)(out + e) = o;
}

// ---------------------------------------------------------------------------
extern "C" void kernel_launch(void* const* d_in, const int* in_sizes, int n_in,
                              void* d_out, int out_size, void* d_ws,
                              size_t ws_size, hipStream_t stream) {
  const float* x      = (const float*)d_in[0];
  const float* W_in   = (const float*)d_in[1];
  const float* b_in   = (const float*)d_in[2];
  const float* Wf_r   = (const float*)d_in[3];
  const float* Wf_i   = (const float*)d_in[4];
  const float* W_out  = (const float*)d_in[5];
  const float* b_out  = (const float*)d_in[6];  // cancels in decomposition
  const float* W_c1   = (const float*)d_in[7];
  const float* W_c2   = (const float*)d_in[8];
  const float* gamma  = (const float*)d_in[9];
  const float* beta   = (const float*)d_in[10];
  float* outp = (float*)d_out;
  (void)b_out;

  // ---- workspace layout ----
  float* f = (float*)d_ws;
  float* buf0 = f;                                   // NBIG region
  bf16*  resbf = (bf16*)buf0;                        // res as bf16 (F2 out)
  // aliases inside buf0 (all dead before F2 writes res):
  float* XFp_r = buf0;                               // 8*524288 f
  float* XFp_i = XFp_r + (size_t)8 * 524288;         // 8*524288 f
  bf16*  Wcat2 = (bf16*)(XFp_i + (size_t)8 * 524288);// 32*512*1024 bf16 (32MB)
  bf16*  Woutbf= Wcat2 + (size_t)32 * 512 * 1024;    // 262144 bf16
  bf16*  Aneg  = Woutbf + 262144;                    // 1048576 bf16
  bf16*  Aswap = Aneg + 1048576;                     // 1048576 bf16
  bf16*  OMr   = Aswap + 1048576;                    // 524288 bf16
  bf16*  OMi   = OMr + 524288;                       // 524288 bf16
  bf16*  CCT   = OMi + 524288;                       // 1048576 bf16
  // tail after buf0:
  float* TwP   = f + NBIG;                           // 131072 f
  float* TbF   = TwP + 131072;                       // 131072 f
  bf16*  TbD   = (bf16*)(TbF + 131072);              // 131072 bf16
  bf16*  Wibf  = TbD + 131072;                       // 262144 bf16 x3
  bf16*  W1bf  = Wibf + 262144;
  bf16*  W2bf  = W1bf + 262144;
  float* meanb = (float*)(W2bf + 262144);
  float* rstdb = meanb + L_;

  // d_out double-duty: [ - |qbf] -> [ - |ubf] -> [xrbf|ubf] -> [xrbf|y1bf]
  bf16* qbf  = ((bf16*)d_out) + NBIG;
  bf16* ubf  = qbf;                 // alias: qbf dead after stageB
  bf16* xrbf = (bf16*)d_out;        // 1st half: free until gemmD writes it
  bf16* y1bf = qbf;                 // alias: ubf dead after gemmD

  // tables + dtype conversions (weights only — x is consumed fp32 directly)
  genTwP<<<512, 256, 0, stream>>>(TwP);
  genTbF<<<512, 256, 0, stream>>>(TbF);
  genTbDbf<<<512, 256, 0, stream>>>(TbF, TbD);
  f2bfK<<<256, 256, 0, stream>>>((const float4*)W_in, (ushort4*)Wibf, 65536);
  f2bfK<<<256, 256, 0, stream>>>((const float4*)W_c1, (ushort4*)W1bf, 65536);
  f2bfK<<<256, 256, 0, stream>>>((const float4*)W_c2, (ushort4*)W2bf, 65536);
  f2bfK<<<256, 256, 0, stream>>>((const float4*)W_out, (ushort4*)Woutbf, 65536);
  // Wf transpose -> Wcat2[m][o][R|I]  (no weight-fold GEMMs anymore)
  twWf2<<<dim3(8, 64, 2), 256, 0, stream>>>(Wf_r, Wf_i, Wcat2);

  // A: q = x @ W_in^T + b_in  (fp32 A reg-staged in-kernel; bf16 out)
  gemm_k64<false, false, true, true, false, true><<<2048, 256, 0, stream>>>(
      x, Wibf, b_in, nullptr, qbf, BLROWS, D_, D_);

  // B: forward DFT partials + reduce/pack
  stageB<<<dim3(B_, 8, 8), 256, 0, stream>>>(qbf, TwP, XFp_r, XFp_i);
  reduceXFT<<<dim3(B_, 8), 256, 0, stream>>>(XFp_r, XFp_i, Aneg, Aswap);

  // OM GEMMs: OM[b*32+m][o] = XFpack @ Wcat2[m]^T  (bf16 out)
  gemm_bt<false, true, true, 0><<<dim3(1, 4, 32), 256, 0, stream>>>(
      Aneg, Wcat2, nullptr, OMr, 32, 512, 1024, 32768, 524288, 512, 16384, 0);
  gemm_bt<false, true, true, 0><<<dim3(1, 4, 32), 256, 0, stream>>>(
      Aswap, Wcat2, nullptr, OMi, 32, 512, 1024, 32768, 524288, 512, 16384, 0);

  // G GEMMs: fold W_out at runtime -> scaled CCT[b][d][64]
  gemm_bt<false, true, false, 3><<<dim3(8, 4, 1), 256, 0, stream>>>(
      OMr, Woutbf, nullptr, CCT, 1024, 512, 512, 0, 0, 0, 0, 0);
  gemm_bt<false, true, false, 4><<<dim3(8, 4, 1), 256, 0, stream>>>(
      OMi, Woutbf, nullptr, CCT, 1024, 512, 512, 0, 0, 0, 0, 0);

  // E: u = x - MA(x) -> ubf (2nd half; qbf dead)  [1024 blocks]
  stageE<<<dim3(B_, 2, 16), 256, 0, stream>>>(x, ubf);

  // D: xr = u + TbD @ CCT^T  -> xrbf (1st half)
  gemmD<<<dim3(16, 4, 32), 256, 0, stream>>>(TbD, CCT, (const ushort*)ubf,
                                             (ushort*)xrbf);

  // F1: y1 = gelu(xr @ Wc1^T)  (bf16 out -> 2nd half; ubf dead)
  gemm_k64<true, false, false, true, false, false><<<2048, 256, 0, stream>>>(
      xrbf, W1bf, nullptr, nullptr, y1bf, BLROWS, D_, D_);

  // F2: res = xr + y1 @ Wc2^T  (bf16 -> resbf in buf0; resid read as bf16)
  gemm_k64<false, true, false, true, true, false><<<2048, 256, 0, stream>>>(
      y1bf, W2bf, nullptr, xrbf, resbf, BLROWS, D_, D_);

  // G: BatchNorm over (b, d) per l  (res read as bf16)
  bnStats<<<L_, 256, 0, stream>>>((const ushort*)resbf, meanb, rstdb);
  bnApply<<<(NBIG / 4 + 255) / 256, 256, 0, stream>>>(
      (const ushort*)resbf, gamma, beta, meanb, rstdb, outp);
}

// Round 15
// 599.992 us; speedup vs baseline: 1.3020x; 1.1422x over previous
//
#include <hip/hip_runtime.h>
#include <hip/hip_bf16.h>
#include <math.h>

#define B_   32
#define L_   2048
#define D_   512
#define BLROWS (B_*L_)                 // 65536
#define NBIG ((size_t)BLROWS * D_)     // 33554432

typedef __hip_bfloat16 bf16;
using bf16x8 = __attribute__((ext_vector_type(8))) short;
using f32x4  = __attribute__((ext_vector_type(4))) float;

__device__ __forceinline__ unsigned short f2b(float f) {
  bf16 h = __float2bfloat16(f);
  return *reinterpret_cast<unsigned short*>(&h);
}
__device__ __forceinline__ float b2f(unsigned short u) {
  union { unsigned int i; float f; } c;
  c.i = ((unsigned int)u) << 16;
  return c.f;
}

__device__ __forceinline__ void gl_lds16(const void* g, void* l) {
  __builtin_amdgcn_global_load_lds(
      (const __attribute__((address_space(1))) void*)g,
      (__attribute__((address_space(3))) void*)l, 16, 0, 0);
}

// ---------------------------------------------------------------------------
// fp32 -> bf16 vectorized converter (weights only)
// ---------------------------------------------------------------------------
__global__ __launch_bounds__(256) void f2bfK(const float4* __restrict__ src,
                                             ushort4* __restrict__ dst,
                                             size_t n4) {
  for (size_t i = (size_t)blockIdx.x * 256 + threadIdx.x; i < n4;
       i += (size_t)gridDim.x * 256) {
    float4 v = src[i];
    ushort4 o;
    o.x = f2b(v.x); o.y = f2b(v.y); o.z = f2b(v.z); o.w = f2b(v.w);
    dst[i] = o;
  }
}

// ---------------------------------------------------------------------------
// Twiddle tables.
// TwCS[64][2048] bf16: row m<32 -> cos(2pi*m*l/L); row 32+m -> -sin(...).
// TbF fp32 inverse basis; TbD = TbF - movavg (bf16).
// ---------------------------------------------------------------------------
__global__ __launch_bounds__(256) void genTwCS(bf16* __restrict__ TwCS) {
  int idx = blockIdx.x * 256 + threadIdx.x;   // mrow*2048 + l ; 131072
  int mrow = idx >> 11, l = idx & 2047;
  int m = mrow & 31;
  int r = (m * l) & (L_ - 1);
  float ang = (float)r * (6.283185307179586f / (float)L_);
  TwCS[idx] = __float2bfloat16((mrow < 32) ? cosf(ang) : -sinf(ang));
}

__global__ __launch_bounds__(256) void genTbF(float* __restrict__ Tb) {
  int idx = blockIdx.x * 256 + threadIdx.x;   // l*64 + j ; 131072
  int l = idx >> 6, j = idx & 63;
  int m = j >> 1;
  int r = (m * l) & (L_ - 1);
  float ang = (float)r * (6.283185307179586f / (float)L_);
  Tb[idx] = (j & 1) ? sinf(ang) : cosf(ang);
}

__global__ __launch_bounds__(256) void genTbDbf(const float* __restrict__ Tb,
                                                bf16* __restrict__ TbD) {
  int idx = blockIdx.x * 256 + threadIdx.x;   // l*64 + j ; 131072
  int l = idx >> 6, j = idx & 63;
  float s = 0.f;
  for (int t = l - 64; t < l + 64; t++) {
    int cl = min(max(t, 0), L_ - 1);
    s += Tb[cl * 64 + j];
  }
  TbD[idx] = __float2bfloat16(Tb[idx] - s * (1.f / 128.f));
}

// ---------------------------------------------------------------------------
// twWf2: Wf_{r,i}[i][o][m] fp32 -> Wcat2[m][o][k] bf16 (k<512 R, >=512 I)
// ---------------------------------------------------------------------------
__global__ __launch_bounds__(256) void twWf2(const float* __restrict__ Wfr,
                                             const float* __restrict__ Wfi,
                                             bf16* __restrict__ Wcat2) {
  __shared__ __align__(16) bf16 st[256 * 72];   // [om][i] padded, 36 KB
  const int t = threadIdx.x;
  const int i0 = blockIdx.x * 64, o0 = blockIdx.y * 8;
  const int arr = blockIdx.z;
  const float* src = arr ? Wfi : Wfr;
#pragma unroll
  for (int s8 = 0; s8 < 8; s8++) {
    unsigned short v[8];
#pragma unroll
    for (int ss = 0; ss < 8; ss++)
      v[ss] = f2b(src[(size_t)(i0 + s8 * 8 + ss) * 16384 + o0 * 32 + t]);
    int4 wv;
    wv.x = (int)v[0] | ((int)v[1] << 16);
    wv.y = (int)v[2] | ((int)v[3] << 16);
    wv.z = (int)v[4] | ((int)v[5] << 16);
    wv.w = (int)v[6] | ((int)v[7] << 16);
    *(int4*)&st[t * 72 + s8 * 8] = wv;
  }
  __syncthreads();
#pragma unroll
  for (int p = 0; p < 8; p++) {
    const int om = p * 32 + (t >> 3), c = t & 7;
    const int o = om >> 5, m = om & 31;
    int4 rv = *(const int4*)&st[om * 72 + c * 8];
    bf16* dst = Wcat2 + (size_t)m * 524288 + (size_t)(o0 + o) * 1024 +
                arr * 512 + i0 + c * 8;
    *(int4*)dst = rv;
  }
}

// ---------------------------------------------------------------------------
// gemm_k64: 128x128 tile, BK=64, 2-buf __syncthreads pipeline (replay-proven),
// XOR-swizzled LDS both operands (verified conflict-free), transposed MFMA
// (C^T = mfma(B,A)) -> d-major vectorized epilogue.  XCD-pairing grid.
// AFP32: A read fp32, reg-staged cvt+ds_write_b128.
// DFTE (GEMM A only): instead of writing q, fuse the forward DFT:
//   q tile (bias added) -> QT[i][l] in LDS (XOR swz) -> 32 MFMA/wave against
//   the TwCS[64][2048] cos/-sin table -> bf16 partials
//   Pdft[(b*16+lblk)*64 + mrow][512 i]  (mrow<32 real, >=32 imag).
// ---------------------------------------------------------------------------
template <bool GELU, bool RESID, bool BIAS, bool OUTBF, bool RESBF, bool AFP32,
          bool DFTE>
__global__ __launch_bounds__(256) void gemm_k64(
    const void* __restrict__ Av, const bf16* __restrict__ Wt,
    const float* __restrict__ bias, const void* __restrict__ resid,
    void* __restrict__ Cout, int M, int N, int K,
    const bf16* __restrict__ TwCS, bf16* __restrict__ Pdft) {
  __shared__ __align__(16) bf16 As[2][128 * 64];   // 16 KB each
  __shared__ __align__(16) bf16 Bs[2][128 * 64];
  const int t = threadIdx.x;
  const int lane = t & 63;
  const int w = t >> 6, wr = w >> 1, wc = w & 1;

  const int id = blockIdx.x;
  const int xcd = id & 7, rest = id >> 3;
  const int cb = rest & 3, rg = rest >> 2;
  const int row0 = (rg * 8 + xcd) * 128, col0 = cb * 128;

  const bf16* Ab = (const bf16*)Av;
  const float* Af = (const float*)Av;

  f32x4 acc[4][4];   // acc[n][m] = C^T fragment
#pragma unroll
  for (int i = 0; i < 4; i++)
#pragma unroll
    for (int j = 0; j < 4; j++) acc[i][j] = (f32x4){0.f, 0.f, 0.f, 0.f};

  auto stage = [&](int buf, int k0) {
#pragma unroll
    for (int s = 0; s < 4; s++) {
      const int ci = s * 256 + t;
      const int row = ci >> 3;
      const int cg = ci & 7;
      const int pc = cg ^ (row & 7);
      if (AFP32) {
        const float* ax = Af + (size_t)(row0 + row) * K + k0 + cg * 8;
        float4 v0 = *(const float4*)(ax);
        float4 v1 = *(const float4*)(ax + 4);
        int4 wv;
        wv.x = (int)f2b(v0.x) | ((int)f2b(v0.y) << 16);
        wv.y = (int)f2b(v0.z) | ((int)f2b(v0.w) << 16);
        wv.z = (int)f2b(v1.x) | ((int)f2b(v1.y) << 16);
        wv.w = (int)f2b(v1.z) | ((int)f2b(v1.w) << 16);
        *(int4*)&As[buf][(size_t)(row * 8 + pc) * 8] = wv;
      } else {
        const int kqg = cg ^ (row & 7);
        bf16* dA = &As[buf][(size_t)(s * 256 + (t & ~63)) * 8];
        gl_lds16(Ab + (size_t)(row0 + row) * K + k0 + kqg * 8, dA);
      }
      {
        const int kqg = cg ^ (row & 7);
        bf16* dB = &Bs[buf][(size_t)(s * 256 + (t & ~63)) * 8];
        gl_lds16(Wt + (size_t)(col0 + row) * K + k0 + kqg * 8, dB);
      }
    }
  };

  stage(0, 0);
  int cur = 0;
  for (int k0 = 0; k0 < K; k0 += 64) {
    __syncthreads();                   // drains stage(cur); prev reads done
    if (k0 + 64 < K) stage(cur ^ 1, k0 + 64);
#pragma unroll
    for (int ks = 0; ks < 2; ks++) {
      const int c = ks * 4 + (lane >> 4);        // global k-chunk
      const int pc = c ^ (lane & 7);             // phys (swizzled) chunk
      bf16x8 af[4], bg[4];
#pragma unroll
      for (int m = 0; m < 4; m++) {
        const int ra = wr * 64 + m * 16 + (lane & 15);
        af[m] = *reinterpret_cast<const bf16x8*>(&As[cur][(ra * 8 + pc) * 8]);
      }
#pragma unroll
      for (int n = 0; n < 4; n++) {
        const int rb = wc * 64 + n * 16 + (lane & 15);
        bg[n] = *reinterpret_cast<const bf16x8*>(&Bs[cur][(rb * 8 + pc) * 8]);
      }
#pragma unroll
      for (int n = 0; n < 4; n++)
#pragma unroll
        for (int m = 0; m < 4; m++)
          acc[n][m] = __builtin_amdgcn_mfma_f32_16x16x32_bf16(
              bg[n], af[m], acc[n][m], 0, 0, 0);
    }
    cur ^= 1;
  }

  if (DFTE) {
    // ---- fused forward DFT epilogue (q never goes to global) ----
    bf16* QT = (bf16*)As;              // 128 x 128 bf16 = 32 KB (As reused)
    __syncthreads();                   // all main-loop LDS reads done
#pragma unroll
    for (int n = 0; n < 4; n++) {
      const int ibase = wc * 64 + n * 16 + ((lane >> 4) << 2);
      float4 bsv = *(const float4*)(bias + col0 + ibase);
#pragma unroll
      for (int m = 0; m < 4; m++) {
        const int lloc = wr * 64 + m * 16 + (lane & 15);
#pragma unroll
        for (int j = 0; j < 4; j++) {
          const int iloc = ibase + j;
          float u = acc[n][m][j] + (&bsv.x)[j];
          QT[iloc * 128 + (((lloc >> 3) ^ (iloc & 7)) << 3) + (lloc & 7)] =
              __float2bfloat16(u);
        }
      }
    }
    __syncthreads();
    const int bidx = row0 >> 11, lblk = (row0 >> 7) & 15;
    const int l0g = row0 & 2047;
    f32x4 accd[4][2];
#pragma unroll
    for (int mp = 0; mp < 4; mp++)
#pragma unroll
      for (int ip = 0; ip < 2; ip++) accd[mp][ip] = (f32x4){0.f,0.f,0.f,0.f};
#pragma unroll
    for (int kc = 0; kc < 4; kc++) {
      bf16x8 bgt[4], afq[2];
#pragma unroll
      for (int mp = 0; mp < 4; mp++)
        bgt[mp] = *reinterpret_cast<const bf16x8*>(
            TwCS + (size_t)(mp * 16 + (lane & 15)) * 2048 + l0g + kc * 32 +
            (lane >> 4) * 8);
#pragma unroll
      for (int ip = 0; ip < 2; ip++) {
        const int iloc = (w * 2 + ip) * 16 + (lane & 15);
        const int kchunk = kc * 4 + (lane >> 4);
        const int pcq = kchunk ^ (iloc & 7);
        afq[ip] = *reinterpret_cast<const bf16x8*>(&QT[iloc * 128 + pcq * 8]);
      }
#pragma unroll
      for (int mp = 0; mp < 4; mp++)
#pragma unroll
        for (int ip = 0; ip < 2; ip++)
          accd[mp][ip] = __builtin_amdgcn_mfma_f32_16x16x32_bf16(
              bgt[mp], afq[ip], accd[mp][ip], 0, 0, 0);
    }
    bf16* Pb = Pdft + (size_t)(bidx * 16 + lblk) * 64 * 512;
#pragma unroll
    for (int mp = 0; mp < 4; mp++)
#pragma unroll
      for (int ip = 0; ip < 2; ip++)
#pragma unroll
        for (int j = 0; j < 4; j++) {
          const int mrow = mp * 16 + ((lane >> 4) << 2) + j;
          const int ig = col0 + (w * 2 + ip) * 16 + (lane & 15);
          Pb[(size_t)mrow * 512 + ig] = __float2bfloat16(accd[mp][ip][j]);
        }
    return;
  }

  // transposed epilogue: d-major vector access
  float* Cf = (float*)Cout;
  ushort* Cb = (ushort*)Cout;
#pragma unroll
  for (int n = 0; n < 4; n++) {
    const int dbase = col0 + wc * 64 + n * 16 + ((lane >> 4) << 2);
    float4 bsv = {0.f, 0.f, 0.f, 0.f};
    if (BIAS) bsv = *(const float4*)(bias + dbase);
#pragma unroll
    for (int m = 0; m < 4; m++) {
      const size_t r = (size_t)row0 + wr * 64 + m * 16 + (lane & 15);
      float v[4];
#pragma unroll
      for (int j = 0; j < 4; j++) {
        float u = acc[n][m][j] + (BIAS ? (&bsv.x)[j] : 0.f);
        if (GELU) u = 0.5f * u * (1.0f + erff(u * 0.70710678118654752f));
        v[j] = u;
      }
      if (RESID) {
        if (RESBF) {
          ushort4 rv = *(const ushort4*)((const ushort*)resid + r * N + dbase);
          v[0] += b2f(rv.x); v[1] += b2f(rv.y);
          v[2] += b2f(rv.z); v[3] += b2f(rv.w);
        } else {
          float4 rv = *(const float4*)((const float*)resid + r * N + dbase);
          v[0] += rv.x; v[1] += rv.y; v[2] += rv.z; v[3] += rv.w;
        }
      }
      if (OUTBF) {
        ushort4 o = {f2b(v[0]), f2b(v[1]), f2b(v[2]), f2b(v[3])};
        *(ushort4*)(Cb + r * N + dbase) = o;
      } else {
        float4 o = {v[0], v[1], v[2], v[3]};
        *(float4*)(Cf + r * N + dbase) = o;
      }
    }
  }
}

// ---------------------------------------------------------------------------
// gemmD: xr[b][l][d] = u[b][l][d] + sum_j TbD[l][j] * CCT[b][d][j]
// ---------------------------------------------------------------------------
__global__ __launch_bounds__(256) void gemmD(
    const bf16* __restrict__ TbD, const bf16* __restrict__ CCT,
    const ushort* __restrict__ u, ushort* __restrict__ xr) {
  __shared__ __align__(16) bf16 As[128 * 64];
  __shared__ __align__(16) bf16 Bs[128 * 64];
  const int t = threadIdx.x;
  const int lane = t & 63;
  const int wid = t >> 6, wr = wid >> 1, wc = wid & 1;
  const int row0 = blockIdx.x * 128, col0 = blockIdx.y * 128;
  const int b = blockIdx.z;
  const bf16* Bsrc = CCT + (size_t)b * 512 * 64;

  const int srow = t >> 3, schk = t & 7;
  const int wb16 = (t & ~63) * 8;
#pragma unroll
  for (int p = 0; p < 4; p++) {
    gl_lds16(TbD + (size_t)(row0 + srow + 32 * p) * 64 + schk * 8,
             &As[p * 2048 + wb16]);
    gl_lds16(Bsrc + (size_t)(col0 + srow + 32 * p) * 64 + schk * 8,
             &Bs[p * 2048 + wb16]);
  }
  __syncthreads();

  f32x4 acc[4][4];
#pragma unroll
  for (int i = 0; i < 4; i++)
#pragma unroll
    for (int j = 0; j < 4; j++) acc[i][j] = (f32x4){0.f, 0.f, 0.f, 0.f};

#pragma unroll
  for (int ks = 0; ks < 2; ks++) {
    bf16x8 af[4], bg[4];
#pragma unroll
    for (int m = 0; m < 4; m++)
      af[m] = *reinterpret_cast<const bf16x8*>(
          &As[(wr * 64 + m * 16 + (lane & 15)) * 64 + ks * 32 +
              (lane >> 4) * 8]);
#pragma unroll
    for (int n = 0; n < 4; n++)
      bg[n] = *reinterpret_cast<const bf16x8*>(
          &Bs[(wc * 64 + n * 16 + (lane & 15)) * 64 + ks * 32 +
              (lane >> 4) * 8]);
#pragma unroll
    for (int n = 0; n < 4; n++)
#pragma unroll
      for (int m = 0; m < 4; m++)
        acc[n][m] = __builtin_amdgcn_mfma_f32_16x16x32_bf16(bg[n], af[m],
                                                            acc[n][m], 0, 0, 0);
  }

#pragma unroll
  for (int n = 0; n < 4; n++) {
    const int dbase = col0 + wc * 64 + n * 16 + ((lane >> 4) << 2);
#pragma unroll
    for (int m = 0; m < 4; m++) {
      const int l = row0 + wr * 64 + m * 16 + (lane & 15);
      const size_t rg = ((size_t)b * L_ + l) * D_ + dbase;
      ushort4 uv = *(const ushort4*)(u + rg);
      ushort4 o;
      o.x = f2b(acc[n][m][0] + b2f(uv.x));
      o.y = f2b(acc[n][m][1] + b2f(uv.y));
      o.z = f2b(acc[n][m][2] + b2f(uv.z));
      o.w = f2b(acc[n][m][3] + b2f(uv.w));
      *(ushort4*)(xr + rg) = o;
    }
  }
}

// ---------------------------------------------------------------------------
// gemm_bt (2-buf): OM GEMMs (EPI 0) and G GEMMs (EPI 3 real / 4 imag CCT).
// ---------------------------------------------------------------------------
template <bool BIAS, bool OUTBF, bool MGUARD, int EPI>
__global__ __launch_bounds__(256) void gemm_bt(
    const bf16* __restrict__ A, const bf16* __restrict__ Wt,
    const float* __restrict__ bias, void* __restrict__ Cout,
    int M, int N, int K, long batchA, long batchB, long batchC,
    int ldc, int coff) {
  __shared__ __align__(16) bf16 As[2][128 * 32];
  __shared__ __align__(16) bf16 Bs[2][128 * 32];
  const int t = threadIdx.x;
  const int lane = t & 63;
  const int wid = t >> 6, wr = wid >> 1, wc = wid & 1;
  const int row0 = blockIdx.x * 128, col0 = blockIdx.y * 128;
  const int zb = blockIdx.z;
  A += (size_t)zb * (size_t)batchA;
  Wt += (size_t)zb * (size_t)batchB;

  f32x4 acc[4][4];
#pragma unroll
  for (int i = 0; i < 4; i++)
#pragma unroll
    for (int j = 0; j < 4; j++) acc[i][j] = (f32x4){0.f, 0.f, 0.f, 0.f};

  const int srow = t >> 2, scq = t & 3;
  const int sa0 = MGUARD ? (srow & 31) : srow;
  const int sa1 = MGUARD ? (srow & 31) : (64 + srow);
  const int wbase = (t & ~63) * 8;

  auto stage = [&](int buf, int k0) {
    gl_lds16(A + (size_t)(row0 + sa0) * K + k0 + scq * 8, &As[buf][wbase]);
    gl_lds16(A + (size_t)(row0 + sa1) * K + k0 + scq * 8,
             &As[buf][2048 + wbase]);
    gl_lds16(Wt + (size_t)(col0 + srow) * K + k0 + scq * 8, &Bs[buf][wbase]);
    gl_lds16(Wt + (size_t)(col0 + 64 + srow) * K + k0 + scq * 8,
             &Bs[buf][2048 + wbase]);
  };

  stage(0, 0);
  int cur = 0;
  for (int k0 = 0; k0 < K; k0 += 32) {
    __syncthreads();
    if (k0 + 32 < K) stage(cur ^ 1, k0 + 32);
    bf16x8 af[4], bg[4];
#pragma unroll
    for (int m = 0; m < 4; m++)
      af[m] = *reinterpret_cast<const bf16x8*>(
          &As[cur][(wr * 64 + m * 16 + (lane & 15)) * 32 + (lane >> 4) * 8]);
#pragma unroll
    for (int n = 0; n < 4; n++)
      bg[n] = *reinterpret_cast<const bf16x8*>(
          &Bs[cur][(wc * 64 + n * 16 + (lane & 15)) * 32 + (lane >> 4) * 8]);
#pragma unroll
    for (int m = 0; m < 4; m++)
#pragma unroll
      for (int n = 0; n < 4; n++)
        acc[m][n] = __builtin_amdgcn_mfma_f32_16x16x32_bf16(af[m], bg[n],
                                                            acc[m][n], 0, 0, 0);
    cur ^= 1;
  }

  if (EPI == 3 || EPI == 4) {
    bf16* Cb = (bf16*)Cout;
#pragma unroll
    for (int n = 0; n < 4; n++) {
      int col = col0 + wc * 64 + n * 16 + (lane & 15);
#pragma unroll
      for (int m = 0; m < 4; m++) {
#pragma unroll
        for (int j = 0; j < 4; j++) {
          int row = row0 + wr * 64 + m * 16 + (lane >> 4) * 4 + j;
          int bb = row >> 5, mm = row & 31;
          float scale = (EPI == 3)
              ? ((mm == 0) ? (1.f / (float)L_) : (2.f / (float)L_))
              : (-2.f / (float)L_);
          Cb[((size_t)bb * 512 + col) * 64 + 2 * mm + (EPI == 4 ? 1 : 0)] =
              __float2bfloat16(acc[m][n][j] * scale);
        }
      }
    }
    return;
  }

  float* Cf = (float*)Cout;
  bf16* Cb = (bf16*)Cout;
  const size_t cbase = (size_t)zb * (size_t)batchC;
#pragma unroll
  for (int n = 0; n < 4; n++) {
    int col = col0 + wc * 64 + n * 16 + (lane & 15);
    float bs = 0.f;
    if (BIAS) bs = bias[col];
#pragma unroll
    for (int m = 0; m < 4; m++) {
#pragma unroll
      for (int j = 0; j < 4; j++) {
        int row = row0 + wr * 64 + m * 16 + (lane >> 4) * 4 + j;
        if (MGUARD && row >= M) continue;
        float v = acc[m][n][j] + bs;
        size_t idx = cbase + (size_t)row * ldc + coff + col;
        if (OUTBF) Cb[idx] = __float2bfloat16(v);
        else Cf[idx] = v;
      }
    }
  }
}

// ---------------------------------------------------------------------------
// reduceXFT: sum 16 l-block partials from Pdft, emit packed bf16 A-operands.
// Pdft[(b*16+lb)*64 + mrow][512 i], mrow<32 real, >=32 imag.
// ---------------------------------------------------------------------------
__global__ __launch_bounds__(256) void reduceXFT(
    const bf16* __restrict__ Pdft,
    bf16* __restrict__ Aneg, bf16* __restrict__ Aswap) {
  const int b = blockIdx.x, ic = blockIdx.y;
  const int i0 = ic * 64;
#pragma unroll
  for (int s = 0; s < 8; s++) {
    int flat = s * 256 + threadIdx.x;       // 2048 = 32 m x 64 i
    int m = flat >> 6, i = flat & 63;
    float sr = 0.f, si = 0.f;
#pragma unroll
    for (int lb = 0; lb < 16; lb++) {
      const bf16* base = Pdft + (size_t)(b * 16 + lb) * 64 * 512;
      sr += b2f(*(const unsigned short*)&base[(size_t)m * 512 + i0 + i]);
      si += b2f(*(const unsigned short*)&base[(size_t)(32 + m) * 512 + i0 + i]);
    }
    size_t ab = ((size_t)m * B_ + b) * 1024;
    Aneg[ab + i0 + i] = __float2bfloat16(sr);
    Aneg[ab + 512 + i0 + i] = __float2bfloat16(-si);
    Aswap[ab + i0 + i] = __float2bfloat16(si);
    Aswap[ab + 512 + i0 + i] = __float2bfloat16(sr);
  }
}

// ---------------------------------------------------------------------------
// Stage E: u = x - movavg(x)  (rolling window, replicate pad 64/63), bf16 out.
// ---------------------------------------------------------------------------
__global__ __launch_bounds__(256) void stageE(const float* __restrict__ in,
                                              bf16* __restrict__ outbf) {
  const int b = blockIdx.x, dg = blockIdx.y, lc = blockIdx.z;
  const int d = dg * 256 + threadIdx.x;
  const float* col = in + (size_t)b * L_ * D_ + d;
  bf16* bcol = outbf + (size_t)b * L_ * D_ + d;
  const int l0 = lc * 128;
  float Wsum = 0.f;
  for (int s = l0 - 64; s < l0 + 64; s++) {
    int cl = min(max(s, 0), L_ - 1);
    Wsum += col[(size_t)cl * D_];
  }
  for (int l = l0; l < l0 + 128; l++) {
    float v = col[(size_t)l * D_];
    bcol[(size_t)l * D_] = __float2bfloat16(v - Wsum * (1.f / 128.f));
    int fa = min(l + 64, L_ - 1);
    int fb = max(l - 64, 0);
    Wsum += col[(size_t)fa * D_] - col[(size_t)fb * D_];
  }
}

// ---------------------------------------------------------------------------
// BatchNorm over (b, d) per time step l — res read as bf16.
// ---------------------------------------------------------------------------
__global__ __launch_bounds__(256) void bnStats(const ushort* __restrict__ res,
                                               float* __restrict__ meanb,
                                               float* __restrict__ rstdb) {
  const int l = blockIdx.x;
  const int t = threadIdx.x;
  float s = 0.f, s2 = 0.f;
  for (int b = 0; b < B_; b++) {
    const ushort* p = res + ((size_t)b * L_ + l) * D_ + 2 * t;
    ushort2 v2 = *(const ushort2*)p;
    float a = b2f(v2.x), c = b2f(v2.y);
    s += a + c;
    s2 += a * a + c * c;
  }
#pragma unroll
  for (int off = 32; off > 0; off >>= 1) {
    s += __shfl_down(s, off, 64);
    s2 += __shfl_down(s2, off, 64);
  }
  __shared__ float shs[4], shs2[4];
  int wid = t >> 6;
  if ((t & 63) == 0) { shs[wid] = s; shs2[wid] = s2; }
  __syncthreads();
  if (t == 0) {
    float S = shs[0] + shs[1] + shs[2] + shs[3];
    float S2 = shs2[0] + shs2[1] + shs2[2] + shs2[3];
    const float inv = 1.f / (float)(B_ * D_);
    float mean = S * inv;
    float var = S2 * inv - mean * mean;
    meanb[l] = mean;
    rstdb[l] = rsqrtf(var + 1e-5f);
  }
}

__global__ __launch_bounds__(256) void bnApply(
    const ushort* __restrict__ res, const float* __restrict__ gamma,
    const float* __restrict__ beta, const float* __restrict__ meanb,
    const float* __restrict__ rstdb, float* __restrict__ out) {
  size_t idx = (size_t)blockIdx.x * 256 + threadIdx.x;   // 4-elem index
  if (idx >= NBIG / 4) return;
  size_t e = idx * 4;
  int l = (int)((e >> 9) & (L_ - 1));
  ushort4 v = *(const ushort4*)(res + e);
  float m = meanb[l], rs = rstdb[l];
  float g = gamma[l] * rs, bt = beta[l];
  float4 o;
  o.x = (b2f(v.x) - m) * g + bt;
  o.y = (b2f(v.y) - m) * g + bt;
  o.z = (b2f(v.z) - m) * g + bt;
  o.w = (b2f(v.w) - m) * g + bt;
  *(float4*)(out + e) = o;
}

// ---------------------------------------------------------------------------
extern "C" void kernel_launch(void* const* d_in, const int* in_sizes, int n_in,
                              void* d_out, int out_size, void* d_ws,
                              size_t ws_size, hipStream_t stream) {
  const float* x      = (const float*)d_in[0];
  const float* W_in   = (const float*)d_in[1];
  const float* b_in   = (const float*)d_in[2];
  const float* Wf_r   = (const float*)d_in[3];
  const float* Wf_i   = (const float*)d_in[4];
  const float* W_out  = (const float*)d_in[5];
  const float* b_out  = (const float*)d_in[6];  // cancels in decomposition
  const float* W_c1   = (const float*)d_in[7];
  const float* W_c2   = (const float*)d_in[8];
  const float* gamma  = (const float*)d_in[9];
  const float* beta   = (const float*)d_in[10];
  float* outp = (float*)d_out;
  (void)b_out;

  // ---- workspace layout ----
  float* f = (float*)d_ws;
  float* buf0 = f;                                   // NBIG region
  bf16*  resbf = (bf16*)buf0;                        // res as bf16 (F2 out)
  // aliases inside buf0 (all dead before F2 writes res):
  bf16*  Pdft  = (bf16*)buf0;                        // 512*64*512 bf16 (32MB)
  bf16*  Wcat2 = Pdft + (size_t)512 * 64 * 512;      // 32*512*1024 bf16 (32MB)
  bf16*  Woutbf= Wcat2 + (size_t)32 * 512 * 1024;    // 262144 bf16
  bf16*  Aneg  = Woutbf + 262144;                    // 1048576 bf16
  bf16*  Aswap = Aneg + 1048576;                     // 1048576 bf16
  bf16*  OMr   = Aswap + 1048576;                    // 524288 bf16
  bf16*  OMi   = OMr + 524288;                       // 524288 bf16
  bf16*  CCT   = OMi + 524288;                       // 1048576 bf16
  // tail after buf0:
  bf16*  TwCS  = (bf16*)(f + NBIG);                  // 131072 bf16
  float* TbF   = (float*)(TwCS + 131072);            // 131072 f
  bf16*  TbD   = (bf16*)(TbF + 131072);              // 131072 bf16
  bf16*  Wibf  = TbD + 131072;                       // 262144 bf16 x3
  bf16*  W1bf  = Wibf + 262144;
  bf16*  W2bf  = W1bf + 262144;
  float* meanb = (float*)(W2bf + 262144);
  float* rstdb = meanb + L_;

  // d_out double-duty: [ - |ubf] -> [xrbf|ubf] -> [xrbf|y1bf]
  bf16* ubf  = ((bf16*)d_out) + NBIG;
  bf16* xrbf = (bf16*)d_out;        // 1st half: free until gemmD writes it
  bf16* y1bf = ubf;                 // alias: ubf dead after gemmD

  // tables + dtype conversions (weights only — x is consumed fp32 directly)
  genTwCS<<<512, 256, 0, stream>>>(TwCS);
  genTbF<<<512, 256, 0, stream>>>(TbF);
  genTbDbf<<<512, 256, 0, stream>>>(TbF, TbD);
  f2bfK<<<256, 256, 0, stream>>>((const float4*)W_in, (ushort4*)Wibf, 65536);
  f2bfK<<<256, 256, 0, stream>>>((const float4*)W_c1, (ushort4*)W1bf, 65536);
  f2bfK<<<256, 256, 0, stream>>>((const float4*)W_c2, (ushort4*)W2bf, 65536);
  f2bfK<<<256, 256, 0, stream>>>((const float4*)W_out, (ushort4*)Woutbf, 65536);
  twWf2<<<dim3(8, 64, 2), 256, 0, stream>>>(Wf_r, Wf_i, Wcat2);

  // A (+fused DFT): partials Pdft <- DFT(x @ W_in^T + b_in); q never stored
  gemm_k64<false, false, true, false, false, true, true>
      <<<2048, 256, 0, stream>>>(
      x, Wibf, b_in, nullptr, nullptr, BLROWS, D_, D_, TwCS, Pdft);

  // reduce partials -> packed A-operands
  reduceXFT<<<dim3(B_, 8), 256, 0, stream>>>(Pdft, Aneg, Aswap);

  // OM GEMMs: OM[b*32+m][o] = XFpack @ Wcat2[m]^T  (bf16 out)
  gemm_bt<false, true, true, 0><<<dim3(1, 4, 32), 256, 0, stream>>>(
      Aneg, Wcat2, nullptr, OMr, 32, 512, 1024, 32768, 524288, 512, 16384, 0);
  gemm_bt<false, true, true, 0><<<dim3(1, 4, 32), 256, 0, stream>>>(
      Aswap, Wcat2, nullptr, OMi, 32, 512, 1024, 32768, 524288, 512, 16384, 0);

  // G GEMMs: fold W_out at runtime -> scaled CCT[b][d][64]
  gemm_bt<false, true, false, 3><<<dim3(8, 4, 1), 256, 0, stream>>>(
      OMr, Woutbf, nullptr, CCT, 1024, 512, 512, 0, 0, 0, 0, 0);
  gemm_bt<false, true, false, 4><<<dim3(8, 4, 1), 256, 0, stream>>>(
      OMi, Woutbf, nullptr, CCT, 1024, 512, 512, 0, 0, 0, 0, 0);

  // E: u = x - MA(x) -> ubf (2nd half)  [1024 blocks]
  stageE<<<dim3(B_, 2, 16), 256, 0, stream>>>(x, ubf);

  // D: xr = u + TbD @ CCT^T  -> xrbf (1st half)
  gemmD<<<dim3(16, 4, 32), 256, 0, stream>>>(TbD, CCT, (const ushort*)ubf,
                                             (ushort*)xrbf);

  // F1: y1 = gelu(xr @ Wc1^T)  (bf16 out -> 2nd half; ubf dead)
  gemm_k64<true, false, false, true, false, false, false>
      <<<2048, 256, 0, stream>>>(
      xrbf, W1bf, nullptr, nullptr, y1bf, BLROWS, D_, D_, nullptr, nullptr);

  // F2: res = xr + y1 @ Wc2^T  (bf16 -> resbf in buf0; resid read as bf16)
  gemm_k64<false, true, false, true, true, false, false>
      <<<2048, 256, 0, stream>>>(
      y1bf, W2bf, nullptr, xrbf, resbf, BLROWS, D_, D_, nullptr, nullptr);

  // G: BatchNorm over (b, d) per l  (res read as bf16)
  bnStats<<<L_, 256, 0, stream>>>((const ushort*)resbf, meanb, rstdb);
  bnApply<<<(NBIG / 4 + 255) / 256, 256, 0, stream>>>(
      (const ushort*)resbf, gamma, beta, meanb, rstdb, outp);
}

// Round 16
// 555.355 us; speedup vs baseline: 1.4066x; 1.0804x over previous
//
#include <hip/hip_runtime.h>
#include <hip/hip_bf16.h>
#include <math.h>

#define B_   32
#define L_   2048
#define D_   512
#define BLROWS (B_*L_)                 // 65536
#define NBIG ((size_t)BLROWS * D_)     // 33554432

typedef __hip_bfloat16 bf16;
using bf16x8 = __attribute__((ext_vector_type(8))) short;
using f32x4  = __attribute__((ext_vector_type(4))) float;

__device__ __forceinline__ unsigned short f2b(float f) {
  bf16 h = __float2bfloat16(f);
  return *reinterpret_cast<unsigned short*>(&h);
}
__device__ __forceinline__ float b2f(unsigned short u) {
  union { unsigned int i; float f; } c;
  c.i = ((unsigned int)u) << 16;
  return c.f;
}

__device__ __forceinline__ void gl_lds16(const void* g, void* l) {
  __builtin_amdgcn_global_load_lds(
      (const __attribute__((address_space(1))) void*)g,
      (__attribute__((address_space(3))) void*)l, 16, 0, 0);
}

// ---------------------------------------------------------------------------
// fp32 -> bf16 vectorized converter (weights only)
// ---------------------------------------------------------------------------
__global__ __launch_bounds__(256) void f2bfK(const float4* __restrict__ src,
                                             ushort4* __restrict__ dst,
                                             size_t n4) {
  for (size_t i = (size_t)blockIdx.x * 256 + threadIdx.x; i < n4;
       i += (size_t)gridDim.x * 256) {
    float4 v = src[i];
    ushort4 o;
    o.x = f2b(v.x); o.y = f2b(v.y); o.z = f2b(v.z); o.w = f2b(v.w);
    dst[i] = o;
  }
}

// ---------------------------------------------------------------------------
// Twiddle tables.
// ---------------------------------------------------------------------------
__global__ __launch_bounds__(256) void genTwCS(bf16* __restrict__ TwCS) {
  int idx = blockIdx.x * 256 + threadIdx.x;   // mrow*2048 + l ; 131072
  int mrow = idx >> 11, l = idx & 2047;
  int m = mrow & 31;
  int r = (m * l) & (L_ - 1);
  float ang = (float)r * (6.283185307179586f / (float)L_);
  TwCS[idx] = __float2bfloat16((mrow < 32) ? cosf(ang) : -sinf(ang));
}

__global__ __launch_bounds__(256) void genTbF(float* __restrict__ Tb) {
  int idx = blockIdx.x * 256 + threadIdx.x;   // l*64 + j ; 131072
  int l = idx >> 6, j = idx & 63;
  int m = j >> 1;
  int r = (m * l) & (L_ - 1);
  float ang = (float)r * (6.283185307179586f / (float)L_);
  Tb[idx] = (j & 1) ? sinf(ang) : cosf(ang);
}

__global__ __launch_bounds__(256) void genTbDbf(const float* __restrict__ Tb,
                                                bf16* __restrict__ TbD) {
  int idx = blockIdx.x * 256 + threadIdx.x;   // l*64 + j ; 131072
  int l = idx >> 6, j = idx & 63;
  float s = 0.f;
  for (int t = l - 64; t < l + 64; t++) {
    int cl = min(max(t, 0), L_ - 1);
    s += Tb[cl * 64 + j];
  }
  TbD[idx] = __float2bfloat16(Tb[idx] - s * (1.f / 128.f));
}

// ---------------------------------------------------------------------------
// twWf2: Wf_{r,i}[i][o][m] fp32 -> Wcat2[m][o][k] bf16 (k<512 R, >=512 I)
// ---------------------------------------------------------------------------
__global__ __launch_bounds__(256) void twWf2(const float* __restrict__ Wfr,
                                             const float* __restrict__ Wfi,
                                             bf16* __restrict__ Wcat2) {
  __shared__ __align__(16) bf16 st[256 * 72];   // [om][i] padded, 36 KB
  const int t = threadIdx.x;
  const int i0 = blockIdx.x * 64, o0 = blockIdx.y * 8;
  const int arr = blockIdx.z;
  const float* src = arr ? Wfi : Wfr;
#pragma unroll
  for (int s8 = 0; s8 < 8; s8++) {
    unsigned short v[8];
#pragma unroll
    for (int ss = 0; ss < 8; ss++)
      v[ss] = f2b(src[(size_t)(i0 + s8 * 8 + ss) * 16384 + o0 * 32 + t]);
    int4 wv;
    wv.x = (int)v[0] | ((int)v[1] << 16);
    wv.y = (int)v[2] | ((int)v[3] << 16);
    wv.z = (int)v[4] | ((int)v[5] << 16);
    wv.w = (int)v[6] | ((int)v[7] << 16);
    *(int4*)&st[t * 72 + s8 * 8] = wv;
  }
  __syncthreads();
#pragma unroll
  for (int p = 0; p < 8; p++) {
    const int om = p * 32 + (t >> 3), c = t & 7;
    const int o = om >> 5, m = om & 31;
    int4 rv = *(const int4*)&st[om * 72 + c * 8];
    bf16* dst = Wcat2 + (size_t)m * 524288 + (size_t)(o0 + o) * 1024 +
                arr * 512 + i0 + c * 8;
    *(int4*)dst = rv;
  }
}

// ---------------------------------------------------------------------------
// gemm_k64: 128x128 tile, BK=64, *512 threads (8 waves, 4x2 grid, 32x64
// per-wave tile)* — doubles wave residency (16 waves/CU) at the same 64 KB
// LDS.  2-buf __syncthreads pipeline (replay-proven), XOR-swizzled LDS
// (verified conflict-free), transposed MFMA (C^T = mfma(B,A)) -> d-major
// vectorized epilogue.  XCD-pairing grid.
// AFP32: A read fp32, reg-staged cvt+ds_write_b128.
// DFTE (GEMM A only): fused forward DFT epilogue (q never stored).
// ---------------------------------------------------------------------------
template <bool GELU, bool RESID, bool BIAS, bool OUTBF, bool RESBF, bool AFP32,
          bool DFTE>
__global__ __launch_bounds__(512) void gemm_k64(
    const void* __restrict__ Av, const bf16* __restrict__ Wt,
    const float* __restrict__ bias, const void* __restrict__ resid,
    void* __restrict__ Cout, int M, int N, int K,
    const bf16* __restrict__ TwCS, bf16* __restrict__ Pdft) {
  __shared__ __align__(16) bf16 As[2][128 * 64];   // 16 KB each
  __shared__ __align__(16) bf16 Bs[2][128 * 64];
  const int t = threadIdx.x;
  const int lane = t & 63;
  const int w = t >> 6;                  // wave 0..7
  const int wr = w >> 1, wc = w & 1;     // 4 (M) x 2 (N) wave grid

  const int id = blockIdx.x;
  const int xcd = id & 7, rest = id >> 3;
  const int cb = rest & 3, rg = rest >> 2;
  const int row0 = (rg * 8 + xcd) * 128, col0 = cb * 128;

  const bf16* Ab = (const bf16*)Av;
  const float* Af = (const float*)Av;

  f32x4 acc[4][2];   // acc[n][m] = C^T fragment (wave tile 32 rows x 64 cols)
#pragma unroll
  for (int i = 0; i < 4; i++)
#pragma unroll
    for (int j = 0; j < 2; j++) acc[i][j] = (f32x4){0.f, 0.f, 0.f, 0.f};

  // staging: 1024 chunks (16B) per operand tile; thread t covers 2 chunks.
  auto stage = [&](int buf, int k0) {
#pragma unroll
    for (int s = 0; s < 2; s++) {
      const int ci = s * 512 + t;
      const int row = ci >> 3;
      const int cg = ci & 7;
      const int pc = cg ^ (row & 7);
      if (AFP32) {
        const float* ax = Af + (size_t)(row0 + row) * K + k0 + cg * 8;
        float4 v0 = *(const float4*)(ax);
        float4 v1 = *(const float4*)(ax + 4);
        int4 wv;
        wv.x = (int)f2b(v0.x) | ((int)f2b(v0.y) << 16);
        wv.y = (int)f2b(v0.z) | ((int)f2b(v0.w) << 16);
        wv.z = (int)f2b(v1.x) | ((int)f2b(v1.y) << 16);
        wv.w = (int)f2b(v1.z) | ((int)f2b(v1.w) << 16);
        *(int4*)&As[buf][(size_t)(row * 8 + pc) * 8] = wv;
      } else {
        const int kqg = cg ^ (row & 7);
        bf16* dA = &As[buf][(size_t)(s * 512 + (t & ~63)) * 8];
        gl_lds16(Ab + (size_t)(row0 + row) * K + k0 + kqg * 8, dA);
      }
      {
        const int kqg = cg ^ (row & 7);
        bf16* dB = &Bs[buf][(size_t)(s * 512 + (t & ~63)) * 8];
        gl_lds16(Wt + (size_t)(col0 + row) * K + k0 + kqg * 8, dB);
      }
    }
  };

  stage(0, 0);
  int cur = 0;
  for (int k0 = 0; k0 < K; k0 += 64) {
    __syncthreads();                   // drains stage(cur); prev reads done
    if (k0 + 64 < K) stage(cur ^ 1, k0 + 64);
#pragma unroll
    for (int ks = 0; ks < 2; ks++) {
      const int c = ks * 4 + (lane >> 4);        // global k-chunk
      const int pc = c ^ (lane & 7);             // phys (swizzled) chunk
      bf16x8 af[2], bg[4];
#pragma unroll
      for (int m = 0; m < 2; m++) {
        const int ra = wr * 32 + m * 16 + (lane & 15);
        af[m] = *reinterpret_cast<const bf16x8*>(&As[cur][(ra * 8 + pc) * 8]);
      }
#pragma unroll
      for (int n = 0; n < 4; n++) {
        const int rb = wc * 64 + n * 16 + (lane & 15);
        bg[n] = *reinterpret_cast<const bf16x8*>(&Bs[cur][(rb * 8 + pc) * 8]);
      }
#pragma unroll
      for (int n = 0; n < 4; n++)
#pragma unroll
        for (int m = 0; m < 2; m++)
          acc[n][m] = __builtin_amdgcn_mfma_f32_16x16x32_bf16(
              bg[n], af[m], acc[n][m], 0, 0, 0);
    }
    cur ^= 1;
  }

  if (DFTE) {
    // ---- fused forward DFT epilogue (q never goes to global) ----
    bf16* QT = (bf16*)As;              // 128 x 128 bf16 = 32 KB (As reused)
    __syncthreads();                   // all main-loop LDS reads done
#pragma unroll
    for (int n = 0; n < 4; n++) {
      const int ibase = wc * 64 + n * 16 + ((lane >> 4) << 2);
      float4 bsv = *(const float4*)(bias + col0 + ibase);
#pragma unroll
      for (int m = 0; m < 2; m++) {
        const int lloc = wr * 32 + m * 16 + (lane & 15);
#pragma unroll
        for (int j = 0; j < 4; j++) {
          const int iloc = ibase + j;
          float u = acc[n][m][j] + (&bsv.x)[j];
          QT[iloc * 128 + (((lloc >> 3) ^ (iloc & 7)) << 3) + (lloc & 7)] =
              __float2bfloat16(u);
        }
      }
    }
    __syncthreads();
    const int bidx = row0 >> 11, lblk = (row0 >> 7) & 15;
    const int l0g = row0 & 2047;
    f32x4 accd[4];                     // 4 mrow-frags x 1 i-frag per wave
#pragma unroll
    for (int mp = 0; mp < 4; mp++) accd[mp] = (f32x4){0.f, 0.f, 0.f, 0.f};
    const int iloc = w * 16 + (lane & 15);   // 8 waves cover i 0..127
#pragma unroll
    for (int kc = 0; kc < 4; kc++) {
      bf16x8 bgt[4], afq;
#pragma unroll
      for (int mp = 0; mp < 4; mp++)
        bgt[mp] = *reinterpret_cast<const bf16x8*>(
            TwCS + (size_t)(mp * 16 + (lane & 15)) * 2048 + l0g + kc * 32 +
            (lane >> 4) * 8);
      {
        const int kchunk = kc * 4 + (lane >> 4);
        const int pcq = kchunk ^ (iloc & 7);
        afq = *reinterpret_cast<const bf16x8*>(&QT[iloc * 128 + pcq * 8]);
      }
#pragma unroll
      for (int mp = 0; mp < 4; mp++)
        accd[mp] = __builtin_amdgcn_mfma_f32_16x16x32_bf16(
            bgt[mp], afq, accd[mp], 0, 0, 0);
    }
    bf16* Pb = Pdft + (size_t)(bidx * 16 + lblk) * 64 * 512;
#pragma unroll
    for (int mp = 0; mp < 4; mp++)
#pragma unroll
      for (int j = 0; j < 4; j++) {
        const int mrow = mp * 16 + ((lane >> 4) << 2) + j;
        const int ig = col0 + iloc;
        Pb[(size_t)mrow * 512 + ig] = __float2bfloat16(accd[mp][j]);
      }
    return;
  }

  // transposed epilogue: d-major vector access
  float* Cf = (float*)Cout;
  ushort* Cb = (ushort*)Cout;
#pragma unroll
  for (int n = 0; n < 4; n++) {
    const int dbase = col0 + wc * 64 + n * 16 + ((lane >> 4) << 2);
    float4 bsv = {0.f, 0.f, 0.f, 0.f};
    if (BIAS) bsv = *(const float4*)(bias + dbase);
#pragma unroll
    for (int m = 0; m < 2; m++) {
      const size_t r = (size_t)row0 + wr * 32 + m * 16 + (lane & 15);
      float v[4];
#pragma unroll
      for (int j = 0; j < 4; j++) {
        float u = acc[n][m][j] + (BIAS ? (&bsv.x)[j] : 0.f);
        if (GELU) u = 0.5f * u * (1.0f + erff(u * 0.70710678118654752f));
        v[j] = u;
      }
      if (RESID) {
        if (RESBF) {
          ushort4 rv = *(const ushort4*)((const ushort*)resid + r * N + dbase);
          v[0] += b2f(rv.x); v[1] += b2f(rv.y);
          v[2] += b2f(rv.z); v[3] += b2f(rv.w);
        } else {
          float4 rv = *(const float4*)((const float*)resid + r * N + dbase);
          v[0] += rv.x; v[1] += rv.y; v[2] += rv.z; v[3] += rv.w;
        }
      }
      if (OUTBF) {
        ushort4 o = {f2b(v[0]), f2b(v[1]), f2b(v[2]), f2b(v[3])};
        *(ushort4*)(Cb + r * N + dbase) = o;
      } else {
        float4 o = {v[0], v[1], v[2], v[3]};
        *(float4*)(Cf + r * N + dbase) = o;
      }
    }
  }
}

// ---------------------------------------------------------------------------
// gemmD: xr[b][l][d] = u[b][l][d] + sum_j TbD[l][j] * CCT[b][d][j]
// ---------------------------------------------------------------------------
__global__ __launch_bounds__(256) void gemmD(
    const bf16* __restrict__ TbD, const bf16* __restrict__ CCT,
    const ushort* __restrict__ u, ushort* __restrict__ xr) {
  __shared__ __align__(16) bf16 As[128 * 64];
  __shared__ __align__(16) bf16 Bs[128 * 64];
  const int t = threadIdx.x;
  const int lane = t & 63;
  const int wid = t >> 6, wr = wid >> 1, wc = wid & 1;
  const int row0 = blockIdx.x * 128, col0 = blockIdx.y * 128;
  const int b = blockIdx.z;
  const bf16* Bsrc = CCT + (size_t)b * 512 * 64;

  const int srow = t >> 3, schk = t & 7;
  const int wb16 = (t & ~63) * 8;
#pragma unroll
  for (int p = 0; p < 4; p++) {
    gl_lds16(TbD + (size_t)(row0 + srow + 32 * p) * 64 + schk * 8,
             &As[p * 2048 + wb16]);
    gl_lds16(Bsrc + (size_t)(col0 + srow + 32 * p) * 64 + schk * 8,
             &Bs[p * 2048 + wb16]);
  }
  __syncthreads();

  f32x4 acc[4][4];
#pragma unroll
  for (int i = 0; i < 4; i++)
#pragma unroll
    for (int j = 0; j < 4; j++) acc[i][j] = (f32x4){0.f, 0.f, 0.f, 0.f};

#pragma unroll
  for (int ks = 0; ks < 2; ks++) {
    bf16x8 af[4], bg[4];
#pragma unroll
    for (int m = 0; m < 4; m++)
      af[m] = *reinterpret_cast<const bf16x8*>(
          &As[(wr * 64 + m * 16 + (lane & 15)) * 64 + ks * 32 +
              (lane >> 4) * 8]);
#pragma unroll
    for (int n = 0; n < 4; n++)
      bg[n] = *reinterpret_cast<const bf16x8*>(
          &Bs[(wc * 64 + n * 16 + (lane & 15)) * 64 + ks * 32 +
              (lane >> 4) * 8]);
#pragma unroll
    for (int n = 0; n < 4; n++)
#pragma unroll
      for (int m = 0; m < 4; m++)
        acc[n][m] = __builtin_amdgcn_mfma_f32_16x16x32_bf16(bg[n], af[m],
                                                            acc[n][m], 0, 0, 0);
  }

#pragma unroll
  for (int n = 0; n < 4; n++) {
    const int dbase = col0 + wc * 64 + n * 16 + ((lane >> 4) << 2);
#pragma unroll
    for (int m = 0; m < 4; m++) {
      const int l = row0 + wr * 64 + m * 16 + (lane & 15);
      const size_t rg = ((size_t)b * L_ + l) * D_ + dbase;
      ushort4 uv = *(const ushort4*)(u + rg);
      ushort4 o;
      o.x = f2b(acc[n][m][0] + b2f(uv.x));
      o.y = f2b(acc[n][m][1] + b2f(uv.y));
      o.z = f2b(acc[n][m][2] + b2f(uv.z));
      o.w = f2b(acc[n][m][3] + b2f(uv.w));
      *(ushort4*)(xr + rg) = o;
    }
  }
}

// ---------------------------------------------------------------------------
// gemm_bt (2-buf): OM GEMMs (EPI 0) and G GEMMs (EPI 3 real / 4 imag CCT).
// ---------------------------------------------------------------------------
template <bool BIAS, bool OUTBF, bool MGUARD, int EPI>
__global__ __launch_bounds__(256) void gemm_bt(
    const bf16* __restrict__ A, const bf16* __restrict__ Wt,
    const float* __restrict__ bias, void* __restrict__ Cout,
    int M, int N, int K, long batchA, long batchB, long batchC,
    int ldc, int coff) {
  __shared__ __align__(16) bf16 As[2][128 * 32];
  __shared__ __align__(16) bf16 Bs[2][128 * 32];
  const int t = threadIdx.x;
  const int lane = t & 63;
  const int wid = t >> 6, wr = wid >> 1, wc = wid & 1;
  const int row0 = blockIdx.x * 128, col0 = blockIdx.y * 128;
  const int zb = blockIdx.z;
  A += (size_t)zb * (size_t)batchA;
  Wt += (size_t)zb * (size_t)batchB;

  f32x4 acc[4][4];
#pragma unroll
  for (int i = 0; i < 4; i++)
#pragma unroll
    for (int j = 0; j < 4; j++) acc[i][j] = (f32x4){0.f, 0.f, 0.f, 0.f};

  const int srow = t >> 2, scq = t & 3;
  const int sa0 = MGUARD ? (srow & 31) : srow;
  const int sa1 = MGUARD ? (srow & 31) : (64 + srow);
  const int wbase = (t & ~63) * 8;

  auto stage = [&](int buf, int k0) {
    gl_lds16(A + (size_t)(row0 + sa0) * K + k0 + scq * 8, &As[buf][wbase]);
    gl_lds16(A + (size_t)(row0 + sa1) * K + k0 + scq * 8,
             &As[buf][2048 + wbase]);
    gl_lds16(Wt + (size_t)(col0 + srow) * K + k0 + scq * 8, &Bs[buf][wbase]);
    gl_lds16(Wt + (size_t)(col0 + 64 + srow) * K + k0 + scq * 8,
             &Bs[buf][2048 + wbase]);
  };

  stage(0, 0);
  int cur = 0;
  for (int k0 = 0; k0 < K; k0 += 32) {
    __syncthreads();
    if (k0 + 32 < K) stage(cur ^ 1, k0 + 32);
    bf16x8 af[4], bg[4];
#pragma unroll
    for (int m = 0; m < 4; m++)
      af[m] = *reinterpret_cast<const bf16x8*>(
          &As[cur][(wr * 64 + m * 16 + (lane & 15)) * 32 + (lane >> 4) * 8]);
#pragma unroll
    for (int n = 0; n < 4; n++)
      bg[n] = *reinterpret_cast<const bf16x8*>(
          &Bs[cur][(wc * 64 + n * 16 + (lane & 15)) * 32 + (lane >> 4) * 8]);
#pragma unroll
    for (int m = 0; m < 4; m++)
#pragma unroll
      for (int n = 0; n < 4; n++)
        acc[m][n] = __builtin_amdgcn_mfma_f32_16x16x32_bf16(af[m], bg[n],
                                                            acc[m][n], 0, 0, 0);
    cur ^= 1;
  }

  if (EPI == 3 || EPI == 4) {
    bf16* Cb = (bf16*)Cout;
#pragma unroll
    for (int n = 0; n < 4; n++) {
      int col = col0 + wc * 64 + n * 16 + (lane & 15);
#pragma unroll
      for (int m = 0; m < 4; m++) {
#pragma unroll
        for (int j = 0; j < 4; j++) {
          int row = row0 + wr * 64 + m * 16 + (lane >> 4) * 4 + j;
          int bb = row >> 5, mm = row & 31;
          float scale = (EPI == 3)
              ? ((mm == 0) ? (1.f / (float)L_) : (2.f / (float)L_))
              : (-2.f / (float)L_);
          Cb[((size_t)bb * 512 + col) * 64 + 2 * mm + (EPI == 4 ? 1 : 0)] =
              __float2bfloat16(acc[m][n][j] * scale);
        }
      }
    }
    return;
  }

  float* Cf = (float*)Cout;
  bf16* Cb = (bf16*)Cout;
  const size_t cbase = (size_t)zb * (size_t)batchC;
#pragma unroll
  for (int n = 0; n < 4; n++) {
    int col = col0 + wc * 64 + n * 16 + (lane & 15);
    float bs = 0.f;
    if (BIAS) bs = bias[col];
#pragma unroll
    for (int m = 0; m < 4; m++) {
#pragma unroll
      for (int j = 0; j < 4; j++) {
        int row = row0 + wr * 64 + m * 16 + (lane >> 4) * 4 + j;
        if (MGUARD && row >= M) continue;
        float v = acc[m][n][j] + bs;
        size_t idx = cbase + (size_t)row * ldc + coff + col;
        if (OUTBF) Cb[idx] = __float2bfloat16(v);
        else Cf[idx] = v;
      }
    }
  }
}

// ---------------------------------------------------------------------------
// reduceXFT: sum 16 l-block partials from Pdft, emit packed bf16 A-operands.
// ---------------------------------------------------------------------------
__global__ __launch_bounds__(256) void reduceXFT(
    const bf16* __restrict__ Pdft,
    bf16* __restrict__ Aneg, bf16* __restrict__ Aswap) {
  const int b = blockIdx.x, ic = blockIdx.y;
  const int i0 = ic * 64;
#pragma unroll
  for (int s = 0; s < 8; s++) {
    int flat = s * 256 + threadIdx.x;       // 2048 = 32 m x 64 i
    int m = flat >> 6, i = flat & 63;
    float sr = 0.f, si = 0.f;
#pragma unroll
    for (int lb = 0; lb < 16; lb++) {
      const bf16* base = Pdft + (size_t)(b * 16 + lb) * 64 * 512;
      sr += b2f(*(const unsigned short*)&base[(size_t)m * 512 + i0 + i]);
      si += b2f(*(const unsigned short*)&base[(size_t)(32 + m) * 512 + i0 + i]);
    }
    size_t ab = ((size_t)m * B_ + b) * 1024;
    Aneg[ab + i0 + i] = __float2bfloat16(sr);
    Aneg[ab + 512 + i0 + i] = __float2bfloat16(-si);
    Aswap[ab + i0 + i] = __float2bfloat16(si);
    Aswap[ab + 512 + i0 + i] = __float2bfloat16(sr);
  }
}

// ---------------------------------------------------------------------------
// Stage E: u = x - movavg(x)  (rolling window, replicate pad 64/63), bf16 out.
// ---------------------------------------------------------------------------
__global__ __launch_bounds__(256) void stageE(const float* __restrict__ in,
                                              bf16* __restrict__ outbf) {
  const int b = blockIdx.x, dg = blockIdx.y, lc = blockIdx.z;
  const int d = dg * 256 + threadIdx.x;
  const float* col = in + (size_t)b * L_ * D_ + d;
  bf16* bcol = outbf + (size_t)b * L_ * D_ + d;
  const int l0 = lc * 128;
  float Wsum = 0.f;
  for (int s = l0 - 64; s < l0 + 64; s++) {
    int cl = min(max(s, 0), L_ - 1);
    Wsum += col[(size_t)cl * D_];
  }
  for (int l = l0; l < l0 + 128; l++) {
    float v = col[(size_t)l * D_];
    bcol[(size_t)l * D_] = __float2bfloat16(v - Wsum * (1.f / 128.f));
    int fa = min(l + 64, L_ - 1);
    int fb = max(l - 64, 0);
    Wsum += col[(size_t)fa * D_] - col[(size_t)fb * D_];
  }
}

// ---------------------------------------------------------------------------
// BatchNorm over (b, d) per time step l — res read as bf16.
// ---------------------------------------------------------------------------
__global__ __launch_bounds__(256) void bnStats(const ushort* __restrict__ res,
                                               float* __restrict__ meanb,
                                               float* __restrict__ rstdb) {
  const int l = blockIdx.x;
  const int t = threadIdx.x;
  float s = 0.f, s2 = 0.f;
  for (int b = 0; b < B_; b++) {
    const ushort* p = res + ((size_t)b * L_ + l) * D_ + 2 * t;
    ushort2 v2 = *(const ushort2*)p;
    float a = b2f(v2.x), c = b2f(v2.y);
    s += a + c;
    s2 += a * a + c * c;
  }
#pragma unroll
  for (int off = 32; off > 0; off >>= 1) {
    s += __shfl_down(s, off, 64);
    s2 += __shfl_down(s2, off, 64);
  }
  __shared__ float shs[4], shs2[4];
  int wid = t >> 6;
  if ((t & 63) == 0) { shs[wid] = s; shs2[wid] = s2; }
  __syncthreads();
  if (t == 0) {
    float S = shs[0] + shs[1] + shs[2] + shs[3];
    float S2 = shs2[0] + shs2[1] + shs2[2] + shs2[3];
    const float inv = 1.f / (float)(B_ * D_);
    float mean = S * inv;
    float var = S2 * inv - mean * mean;
    meanb[l] = mean;
    rstdb[l] = rsqrtf(var + 1e-5f);
  }
}

__global__ __launch_bounds__(256) void bnApply(
    const ushort* __restrict__ res, const float* __restrict__ gamma,
    const float* __restrict__ beta, const float* __restrict__ meanb,
    const float* __restrict__ rstdb, float* __restrict__ out) {
  size_t idx = (size_t)blockIdx.x * 256 + threadIdx.x;   // 4-elem index
  if (idx >= NBIG / 4) return;
  size_t e = idx * 4;
  int l = (int)((e >> 9) & (L_ - 1));
  ushort4 v = *(const ushort4*)(res + e);
  float m = meanb[l], rs = rstdb[l];
  float g = gamma[l] * rs, bt = beta[l];
  float4 o;
  o.x = (b2f(v.x) - m) * g + bt;
  o.y = (b2f(v.y) - m) * g + bt;
  o.z = (b2f(v.z) - m) * g + bt;
  o.w = (b2f(v.w) - m) * g + bt;
  *(float4*)(out + e) = o;
}

// ---------------------------------------------------------------------------
extern "C" void kernel_launch(void* const* d_in, const int* in_sizes, int n_in,
                              void* d_out, int out_size, void* d_ws,
                              size_t ws_size, hipStream_t stream) {
  const float* x      = (const float*)d_in[0];
  const float* W_in   = (const float*)d_in[1];
  const float* b_in   = (const float*)d_in[2];
  const float* Wf_r   = (const float*)d_in[3];
  const float* Wf_i   = (const float*)d_in[4];
  const float* W_out  = (const float*)d_in[5];
  const float* b_out  = (const float*)d_in[6];  // cancels in decomposition
  const float* W_c1   = (const float*)d_in[7];
  const float* W_c2   = (const float*)d_in[8];
  const float* gamma  = (const float*)d_in[9];
  const float* beta   = (const float*)d_in[10];
  float* outp = (float*)d_out;
  (void)b_out;

  // ---- workspace layout ----
  float* f = (float*)d_ws;
  float* buf0 = f;                                   // NBIG region
  bf16*  resbf = (bf16*)buf0;                        // res as bf16 (F2 out)
  // aliases inside buf0 (all dead before F2 writes res):
  bf16*  Pdft  = (bf16*)buf0;                        // 512*64*512 bf16 (32MB)
  bf16*  Wcat2 = Pdft + (size_t)512 * 64 * 512;      // 32*512*1024 bf16 (32MB)
  bf16*  Woutbf= Wcat2 + (size_t)32 * 512 * 1024;    // 262144 bf16
  bf16*  Aneg  = Woutbf + 262144;                    // 1048576 bf16
  bf16*  Aswap = Aneg + 1048576;                     // 1048576 bf16
  bf16*  OMr   = Aswap + 1048576;                    // 524288 bf16
  bf16*  OMi   = OMr + 524288;                       // 524288 bf16
  bf16*  CCT   = OMi + 524288;                       // 1048576 bf16
  // tail after buf0:
  bf16*  TwCS  = (bf16*)(f + NBIG);                  // 131072 bf16
  float* TbF   = (float*)(TwCS + 131072);            // 131072 f
  bf16*  TbD   = (bf16*)(TbF + 131072);              // 131072 bf16
  bf16*  Wibf  = TbD + 131072;                       // 262144 bf16 x3
  bf16*  W1bf  = Wibf + 262144;
  bf16*  W2bf  = W1bf + 262144;
  float* meanb = (float*)(W2bf + 262144);
  float* rstdb = meanb + L_;

  // d_out double-duty: [ - |ubf] -> [xrbf|ubf] -> [xrbf|y1bf]
  bf16* ubf  = ((bf16*)d_out) + NBIG;
  bf16* xrbf = (bf16*)d_out;        // 1st half: free until gemmD writes it
  bf16* y1bf = ubf;                 // alias: ubf dead after gemmD

  // tables + dtype conversions (weights only — x is consumed fp32 directly)
  genTwCS<<<512, 256, 0, stream>>>(TwCS);
  genTbF<<<512, 256, 0, stream>>>(TbF);
  genTbDbf<<<512, 256, 0, stream>>>(TbF, TbD);
  f2bfK<<<256, 256, 0, stream>>>((const float4*)W_in, (ushort4*)Wibf, 65536);
  f2bfK<<<256, 256, 0, stream>>>((const float4*)W_c1, (ushort4*)W1bf, 65536);
  f2bfK<<<256, 256, 0, stream>>>((const float4*)W_c2, (ushort4*)W2bf, 65536);
  f2bfK<<<256, 256, 0, stream>>>((const float4*)W_out, (ushort4*)Woutbf, 65536);
  twWf2<<<dim3(8, 64, 2), 256, 0, stream>>>(Wf_r, Wf_i, Wcat2);

  // A (+fused DFT): partials Pdft <- DFT(x @ W_in^T + b_in); q never stored
  gemm_k64<false, false, true, false, false, true, true>
      <<<2048, 512, 0, stream>>>(
      x, Wibf, b_in, nullptr, nullptr, BLROWS, D_, D_, TwCS, Pdft);

  // reduce partials -> packed A-operands
  reduceXFT<<<dim3(B_, 8), 256, 0, stream>>>(Pdft, Aneg, Aswap);

  // OM GEMMs: OM[b*32+m][o] = XFpack @ Wcat2[m]^T  (bf16 out)
  gemm_bt<false, true, true, 0><<<dim3(1, 4, 32), 256, 0, stream>>>(
      Aneg, Wcat2, nullptr, OMr, 32, 512, 1024, 32768, 524288, 512, 16384, 0);
  gemm_bt<false, true, true, 0><<<dim3(1, 4, 32), 256, 0, stream>>>(
      Aswap, Wcat2, nullptr, OMi, 32, 512, 1024, 32768, 524288, 512, 16384, 0);

  // G GEMMs: fold W_out at runtime -> scaled CCT[b][d][64]
  gemm_bt<false, true, false, 3><<<dim3(8, 4, 1), 256, 0, stream>>>(
      OMr, Woutbf, nullptr, CCT, 1024, 512, 512, 0, 0, 0, 0, 0);
  gemm_bt<false, true, false, 4><<<dim3(8, 4, 1), 256, 0, stream>>>(
      OMi, Woutbf, nullptr, CCT, 1024, 512, 512, 0, 0, 0, 0, 0);

  // E: u = x - MA(x) -> ubf (2nd half)  [1024 blocks]
  stageE<<<dim3(B_, 2, 16), 256, 0, stream>>>(x, ubf);

  // D: xr = u + TbD @ CCT^T  -> xrbf (1st half)
  gemmD<<<dim3(16, 4, 32), 256, 0, stream>>>(TbD, CCT, (const ushort*)ubf,
                                             (ushort*)xrbf);

  // F1: y1 = gelu(xr @ Wc1^T)  (bf16 out -> 2nd half; ubf dead)
  gemm_k64<true, false, false, true, false, false, false>
      <<<2048, 512, 0, stream>>>(
      xrbf, W1bf, nullptr, nullptr, y1bf, BLROWS, D_, D_, nullptr, nullptr);

  // F2: res = xr + y1 @ Wc2^T  (bf16 -> resbf in buf0; resid read as bf16)
  gemm_k64<false, true, false, true, true, false, false>
      <<<2048, 512, 0, stream>>>(
      y1bf, W2bf, nullptr, xrbf, resbf, BLROWS, D_, D_, nullptr, nullptr);

  // G: BatchNorm over (b, d) per l  (res read as bf16)
  bnStats<<<L_, 256, 0, stream>>>((const ushort*)resbf, meanb, rstdb);
  bnApply<<<(NBIG / 4 + 255) / 256, 256, 0, stream>>>(
      (const ushort*)resbf, gamma, beta, meanb, rstdb, outp);
}